// Round 3
// baseline (470.656 us; speedup 1.0000x reference)
//
#include <hip/hip_runtime.h>
#include <math.h>

#define NN 50000
#define EE 800000
#define NPAD 50176   // 196*256
#define CPAD 66

typedef __attribute__((ext_vector_type(8))) short short8v;
typedef __attribute__((ext_vector_type(4))) float f32x4;

static __device__ __forceinline__ short bf16r(float x) {
  union { float f; unsigned u; } v; v.f = x;
  unsigned r = v.u + 0x7FFFu + ((v.u >> 16) & 1u);
  return (short)(r >> 16);
}

// ws layout (float offsets):
//   z     @ 0            65536
//   U     @ 65536        3,200,000
//   cnt   @ 3,265,536    50176 (int)
//   start @ 3,315,712    50176 (int)
//   cur   @ 3,365,888    50176 (int)
//   bsum  @ 3,416,064    256   (int)
//   tq    @ 3,416,320    3,200,000
//   M     @ 6,616,320    4096
//   w2kT  @ 6,620,416    1024 (2048 bf16)
//   w2vT  @ 6,621,440    1024
//   Wlvb  @ 6,622,464    2048 (4096 bf16)
//   Wscb  @ 6,624,512    32768 (65536 bf16)
//   perm  @ 6,657,280    800000 (int)
//   end ~29.9 MB

// ---------- fold: M = (W_q@W_dot)@W_lin_k^T ; W2{k,v}->bf16 frag layout; Wlv->bf16 [o][c] ----------
__global__ __launch_bounds__(256) void fold_kernel(
    const float* __restrict__ Wq, const float* __restrict__ Wdot,
    const float* __restrict__ Wlk, const float* __restrict__ W2k,
    const float* __restrict__ W2v, const float* __restrict__ Wlv,
    float* __restrict__ M, unsigned short* __restrict__ w2kT,
    unsigned short* __restrict__ w2vT, unsigned short* __restrict__ wlvb)
{
  __shared__ float tmp[2048];
  const int tid = threadIdx.x;
#pragma unroll
  for (int r = 0; r < 8; ++r) {
    int idx = tid + r * 256;
    int cin = idx >> 5, d = idx & 31;
    float a = 0.f;
    for (int j = 0; j < 32; ++j) a = fmaf(Wq[cin * 32 + j], Wdot[j * 32 + d], a);
    tmp[idx] = a;
  }
  __syncthreads();
#pragma unroll
  for (int r = 0; r < 16; ++r) {
    int idx = tid + r * 256;
    int cin = idx >> 6, c = idx & 63;
    float a = 0.f;
    for (int d = 0; d < 32; ++d) a = fmaf(tmp[cin * 32 + d], Wlk[c * 32 + d], a);
    M[idx] = a;
  }
#pragma unroll
  for (int r = 0; r < 8; ++r) {
    int idx = tid + r * 256;
    int c = idx >> 5, k = idx & 31, h = k >> 2, a = k & 3;
    w2kT[idx] = (unsigned short)bf16r(W2k[h * 256 + c * 4 + a]);
    w2vT[idx] = (unsigned short)bf16r(W2v[h * 256 + c * 4 + a]);
  }
  // Wlvb[o*64+c] = Wlv[c][o]
#pragma unroll
  for (int r = 0; r < 16; ++r) {
    int idx = tid + r * 256;
    int o = idx >> 6, c = idx & 63;
    wlvb[idx] = (unsigned short)bf16r(Wlv[c * 64 + o]);
  }
}

// ---------- Wscb[(p*64+o)*64+c] = bf16(Wsc[c*1024 + p*64 + o]) ----------
__global__ __launch_bounds__(256) void prep_wsc(
    const float* __restrict__ Wsc, unsigned short* __restrict__ wscb)
{
  int w = blockIdx.x * 256 + threadIdx.x;
  int c = w & 63, o = (w >> 6) & 63, p = w >> 12;
  wscb[w] = (unsigned short)bf16r(Wsc[c * 1024 + p * 64 + o]);
}

// ---------- counting sort ----------
__global__ __launch_bounds__(256) void hist_kernel(
    const int* __restrict__ edst, int* __restrict__ cnt)
{
  int e = blockIdx.x * 256 + threadIdx.x;
  atomicAdd(&cnt[edst[e]], 1);
}

__global__ __launch_bounds__(256) void scanA_kernel(
    const int* __restrict__ cnt, int* __restrict__ start, int* __restrict__ bsum)
{
  __shared__ int s[256];
  const int tid = threadIdx.x;
  const int i = blockIdx.x * 256 + tid;
  int v = cnt[i];
  s[tid] = v;
  __syncthreads();
  for (int off = 1; off < 256; off <<= 1) {
    int t = (tid >= off) ? s[tid - off] : 0;
    __syncthreads();
    s[tid] += t;
    __syncthreads();
  }
  start[i] = s[tid] - v;
  if (tid == 255) bsum[blockIdx.x] = s[255];
}

__global__ __launch_bounds__(256) void scanB_kernel(int* __restrict__ bsum)
{
  __shared__ int s[256];
  const int tid = threadIdx.x;
  int v = (tid < 196) ? bsum[tid] : 0;
  s[tid] = v;
  __syncthreads();
  for (int off = 1; off < 256; off <<= 1) {
    int t = (tid >= off) ? s[tid - off] : 0;
    __syncthreads();
    s[tid] += t;
    __syncthreads();
  }
  if (tid < 196) bsum[tid] = s[tid] - v;
}

__global__ __launch_bounds__(256) void scanC_kernel(
    int* __restrict__ start, const int* __restrict__ bsum, int* __restrict__ cur)
{
  const int i = blockIdx.x * 256 + threadIdx.x;
  int sv = start[i] + bsum[blockIdx.x];
  start[i] = sv;
  cur[i] = sv;
}

__global__ __launch_bounds__(256) void scatter_kernel(
    const int* __restrict__ edst, int* __restrict__ cur, int* __restrict__ perm)
{
  int e = blockIdx.x * 256 + threadIdx.x;
  int r = atomicAdd(&cur[edst[e]], 1);
  perm[r] = e;
}

// ---------- tq = nf @ M ----------
__global__ __launch_bounds__(256) void tq_kernel(
    const float* __restrict__ nf, const float* __restrict__ M, float* __restrict__ tq)
{
  __shared__ float Ml[4096];
  __shared__ float nfl[64 * 68];
  const int tid = threadIdx.x;
  const int base = blockIdx.x * 64;
#pragma unroll
  for (int r = 0; r < 4; ++r) {
    int idx = tid + r * 256;
    reinterpret_cast<float4*>(Ml)[idx] = reinterpret_cast<const float4*>(M)[idx];
  }
#pragma unroll
  for (int r = 0; r < 4; ++r) {
    int idx = tid + r * 256;
    int row = idx >> 4, c4 = idx & 15;
    float4 v = make_float4(0.f, 0.f, 0.f, 0.f);
    if (base + row < NN) v = reinterpret_cast<const float4*>(nf)[(base + row) * 16 + c4];
    *reinterpret_cast<float4*>(&nfl[row * 68 + c4 * 4]) = v;
  }
  __syncthreads();
  const int to = tid & 15, tn = tid >> 4;
  float4 acc[4] = {make_float4(0,0,0,0), make_float4(0,0,0,0),
                   make_float4(0,0,0,0), make_float4(0,0,0,0)};
  for (int c = 0; c < 64; ++c) {
    float4 m = reinterpret_cast<const float4*>(Ml)[c * 16 + to];
#pragma unroll
    for (int i = 0; i < 4; ++i) {
      float x = nfl[(tn * 4 + i) * 68 + c];
      acc[i].x = fmaf(x, m.x, acc[i].x);
      acc[i].y = fmaf(x, m.y, acc[i].y);
      acc[i].z = fmaf(x, m.z, acc[i].z);
      acc[i].w = fmaf(x, m.w, acc[i].w);
    }
  }
#pragma unroll
  for (int i = 0; i < 4; ++i) {
    int n = base + tn * 4 + i;
    if (n < NN) reinterpret_cast<float4*>(tq)[n * 16 + to] = acc[i];
  }
}

// ---------- edge pass: 64 sorted edges/block, fused radial, segmented-reduce epilogue ----------
__global__ __launch_bounds__(256) void edge_kernel(
    const float* __restrict__ nf, const float* __restrict__ ea,
    const float* __restrict__ pos, const int* __restrict__ esrc,
    const int* __restrict__ edst, const float* __restrict__ eb,
    const float* __restrict__ W1k, const float* __restrict__ W1v,
    const float* __restrict__ tq, const unsigned short* __restrict__ w2kT,
    const unsigned short* __restrict__ w2vT, const int* __restrict__ perm,
    float* __restrict__ z, float* __restrict__ U)
{
  __shared__ float ys[64 * CPAD];   // x_src * tq_dst; later reused as msg
  __shared__ float xs[64 * CPAD];   // x_src
  __shared__ float hs[64 * 17];     // radial hidden: [0..7]=hk, [8..15]=hv
  __shared__ float4 eal[64];
  __shared__ int   ed[64];
  __shared__ float cl[64];
  __shared__ float evs[64];
  const int tid  = threadIdx.x;
  const int lane = tid & 63;
  const int lo = lane & 15, hi = lane >> 4;
  const int sb = blockIdx.x * 64;

  // B fragments (loop-invariant)
  short8v bk[4], bv[4];
#pragma unroll
  for (int t = 0; t < 4; ++t) {
    bk[t] = *reinterpret_cast<const short8v*>(&w2kT[(16 * t + lo) * 32 + hi * 8]);
    bv[t] = *reinterpret_cast<const short8v*>(&w2vT[(16 * t + lo) * 32 + hi * 8]);
  }

  // per-edge scalars: dst, ea, cutoff
  if (tid < 64) {
    int eo = perm[sb + tid];
    int s = esrc[eo], d = edst[eo];
    ed[tid] = d;
    eal[tid] = reinterpret_cast<const float4*>(ea)[eo];
    float dx = pos[d * 3 + 0] - pos[s * 3 + 0];
    float dy = pos[d * 3 + 1] - pos[s * 3 + 1];
    float dz = pos[d * 3 + 2] - pos[s * 3 + 2];
    float len = sqrtf(fmaf(dx, dx, fmaf(dy, dy, dz * dz)));
    float arg = 10.f - 2.f * len;
    cl[tid] = (arg > 0.f) ? __expf(-1.f / arg) : 0.f;
  }
  // radial MLP: 4 threads per edge, each computes 2 hk + 2 hv components
  {
    const int eh = tid >> 2, pq = tid & 3;
    const int eo = perm[sb + eh];
    const float4* eb4 = reinterpret_cast<const float4*>(eb);
    float4 q0 = eb4[eo * 4 + 0], q1 = eb4[eo * 4 + 1],
           q2 = eb4[eo * 4 + 2], q3 = eb4[eo * 4 + 3];
    float ebv[16] = {q0.x, q0.y, q0.z, q0.w, q1.x, q1.y, q1.z, q1.w,
                     q2.x, q2.y, q2.z, q2.w, q3.x, q3.y, q3.z, q3.w};
    float a0 = 0.f, a1 = 0.f, b0 = 0.f, b1 = 0.f;
#pragma unroll
    for (int b = 0; b < 16; ++b) {
      float x = ebv[b];
      a0 = fmaf(x, W1k[b * 8 + 2 * pq], a0);
      a1 = fmaf(x, W1k[b * 8 + 2 * pq + 1], a1);
      b0 = fmaf(x, W1v[b * 8 + 2 * pq], b0);
      b1 = fmaf(x, W1v[b * 8 + 2 * pq + 1], b1);
    }
    hs[eh * 17 + 2 * pq]     = a0 / (1.f + __expf(-a0));
    hs[eh * 17 + 2 * pq + 1] = a1 / (1.f + __expf(-a1));
    hs[eh * 17 + 8 + 2 * pq]     = b0 / (1.f + __expf(-b0));
    hs[eh * 17 + 8 + 2 * pq + 1] = b1 / (1.f + __expf(-b1));
  }
  // stage x_src and x_src*tq_dst
#pragma unroll
  for (int r = 0; r < 4; ++r) {
    int idx = tid + r * 256;
    int e = idx >> 4, c4 = idx & 15;
    int eo = perm[sb + e];
    int s = esrc[eo], d = edst[eo];
    float4 xv = reinterpret_cast<const float4*>(nf)[s * 16 + c4];
    float4 tv = reinterpret_cast<const float4*>(tq)[d * 16 + c4];
    float* xp = &xs[e * CPAD + c4 * 4];
    xp[0] = xv.x; xp[1] = xv.y; xp[2] = xv.z; xp[3] = xv.w;
    float* yp = &ys[e * CPAD + c4 * 4];
    yp[0] = xv.x * tv.x; yp[1] = xv.y * tv.y; yp[2] = xv.z * tv.z; yp[3] = xv.w * tv.w;
  }
  __syncthreads();

  // A fragments: A[row=edge][k=h*4+a] = h[h]*ea[a]
  const int w = tid >> 6;
  const int row = 16 * w + lo;
  float hk0 = hs[row * 17 + 2 * hi], hk1 = hs[row * 17 + 2 * hi + 1];
  float hv0 = hs[row * 17 + 8 + 2 * hi], hv1 = hs[row * 17 + 9 + 2 * hi];
  float4 a4 = eal[row];
  short8v ak, av;
  ak[0] = bf16r(hk0 * a4.x); ak[1] = bf16r(hk0 * a4.y);
  ak[2] = bf16r(hk0 * a4.z); ak[3] = bf16r(hk0 * a4.w);
  ak[4] = bf16r(hk1 * a4.x); ak[5] = bf16r(hk1 * a4.y);
  ak[6] = bf16r(hk1 * a4.z); ak[7] = bf16r(hk1 * a4.w);
  av[0] = bf16r(hv0 * a4.x); av[1] = bf16r(hv0 * a4.y);
  av[2] = bf16r(hv0 * a4.z); av[3] = bf16r(hv0 * a4.w);
  av[4] = bf16r(hv1 * a4.x); av[5] = bf16r(hv1 * a4.y);
  av[6] = bf16r(hv1 * a4.z); av[7] = bf16r(hv1 * a4.w);

  f32x4 zero = {0.f, 0.f, 0.f, 0.f};
  f32x4 ack[4], acv[4];
#pragma unroll
  for (int t = 0; t < 4; ++t) {
    ack[t] = __builtin_amdgcn_mfma_f32_16x16x32_bf16(ak, bk[t], zero, 0, 0, 0);
    acv[t] = __builtin_amdgcn_mfma_f32_16x16x32_bf16(av, bv[t], zero, 0, 0, 0);
  }

  // score per C-row (edge erow+i)
  const int erow = 16 * w + 4 * hi;
  float p0, p1, p2, p3;
  {
    const float* y0 = &ys[(erow + 0) * CPAD + lo];
    const float* y1 = &ys[(erow + 1) * CPAD + lo];
    const float* y2 = &ys[(erow + 2) * CPAD + lo];
    const float* y3 = &ys[(erow + 3) * CPAD + lo];
    p0 = y0[0]*ack[0][0] + y0[16]*ack[1][0] + y0[32]*ack[2][0] + y0[48]*ack[3][0];
    p1 = y1[0]*ack[0][1] + y1[16]*ack[1][1] + y1[32]*ack[2][1] + y1[48]*ack[3][1];
    p2 = y2[0]*ack[0][2] + y2[16]*ack[1][2] + y2[32]*ack[2][2] + y2[48]*ack[3][2];
    p3 = y3[0]*ack[0][3] + y3[16]*ack[1][3] + y3[32]*ack[2][3] + y3[48]*ack[3][3];
  }
#pragma unroll
  for (int off = 1; off < 16; off <<= 1) {
    p0 += __shfl_xor(p0, off);
    p1 += __shfl_xor(p1, off);
    p2 += __shfl_xor(p2, off);
    p3 += __shfl_xor(p3, off);
  }
  float ev0 = cl[erow + 0] * __expf(0.5f * p0);
  float ev1 = cl[erow + 1] * __expf(0.5f * p1);
  float ev2 = cl[erow + 2] * __expf(0.5f * p2);
  float ev3 = cl[erow + 3] * __expf(0.5f * p3);
  float se0 = sqrtf(ev0), se1 = sqrtf(ev1), se2 = sqrtf(ev2), se3 = sqrtf(ev3);
  if (lo < 4) {
    float ev = (lo == 0) ? ev0 : (lo == 1) ? ev1 : (lo == 2) ? ev2 : ev3;
    evs[erow + lo] = ev;
  }
  // msg[e][c] = se * x_src[c] * sv[c]  (overwrite ys rows owned by this wave)
#pragma unroll
  for (int i = 0; i < 4; ++i) {
    const float se = (i == 0) ? se0 : (i == 1) ? se1 : (i == 2) ? se2 : se3;
    float* mr = &ys[(erow + i) * CPAD + lo];
    const float* xr = &xs[(erow + i) * CPAD + lo];
#pragma unroll
    for (int t = 0; t < 4; ++t) {
      mr[16 * t] = se * xr[16 * t] * acv[t][i];
    }
  }
  // segmented reduce: wave w walks strip [16w,16w+16), lane = channel
  {
    const int c = lane;
    float acc = 0.f, evacc = 0.f;
    int prev = ed[16 * w];
    for (int r = 16 * w; r < 16 * w + 16; ++r) {
      int d = ed[r];
      if (d != prev) {
        unsafeAtomicAdd(&U[prev * 64 + c], acc);
        if (c == 0) unsafeAtomicAdd(&z[prev], evacc);
        acc = 0.f; evacc = 0.f; prev = d;
      }
      acc += ys[r * CPAD + c];
      if (c == 0) evacc += evs[r];
    }
    unsafeAtomicAdd(&U[prev * 64 + c], acc);
    if (c == 0) unsafeAtomicAdd(&z[prev], evacc);
  }
}

// ---------- final (MFMA): out = s*(U@Wlv) + einsum(nf,na,Wsc) ----------
__global__ __launch_bounds__(256) void final_kernel(
    const float* __restrict__ nf, const float* __restrict__ na,
    const float* __restrict__ U, const float* __restrict__ z,
    const unsigned short* __restrict__ wscb, const unsigned short* __restrict__ wlvb,
    float* __restrict__ out)
{
  __shared__ float nfl[64 * 68];
  __shared__ float Ul[64 * 68];
  __shared__ float nal[64 * 17];
  __shared__ float sl[64];
  const int tid = threadIdx.x;
  const int lane = tid & 63;
  const int lo = lane & 15, hi = lane >> 4;
  const int w = tid >> 6;
  const int nb = blockIdx.x * 64;

#pragma unroll
  for (int r = 0; r < 4; ++r) {
    int idx = tid + r * 256;
    int row = idx >> 4, c4 = idx & 15;
    int n = nb + row; if (n >= NN) n = NN - 1;
    float4 v = reinterpret_cast<const float4*>(nf)[n * 16 + c4];
    *reinterpret_cast<float4*>(&nfl[row * 68 + c4 * 4]) = v;
    float4 u = reinterpret_cast<const float4*>(U)[n * 16 + c4];
    *reinterpret_cast<float4*>(&Ul[row * 68 + c4 * 4]) = u;
  }
#pragma unroll
  for (int r = 0; r < 4; ++r) {
    int idx = tid + r * 256;
    int row = idx >> 4, p = idx & 15;
    int n = nb + row; if (n >= NN) n = NN - 1;
    nal[row * 17 + p] = na[n * 16 + p];
  }
  if (tid < 64) {
    int n = nb + tid; if (n >= NN) n = NN - 1;
    float zz = z[n];
    sl[tid] = (zz > 0.f) ? 0.5f * rsqrtf(zz) : 0.f;
  }
  __syncthreads();

  const int row = 16 * w + lo;
  short8v anf[2], au[2];
#pragma unroll
  for (int kk = 0; kk < 2; ++kk) {
#pragma unroll
    for (int j = 0; j < 8; ++j) {
      anf[kk][j] = bf16r(nfl[row * 68 + 32 * kk + 8 * hi + j]);
      au[kk][j]  = bf16r(Ul[row * 68 + 32 * kk + 8 * hi + j]);
    }
  }

  f32x4 zeroA = {0.f, 0.f, 0.f, 0.f};
  f32x4 accS[4] = {zeroA, zeroA, zeroA, zeroA};
  f32x4 accU[4] = {zeroA, zeroA, zeroA, zeroA};

  // U @ Wlv
#pragma unroll
  for (int t = 0; t < 4; ++t) {
    short8v b0 = *reinterpret_cast<const short8v*>(&wlvb[(16 * t + lo) * 64 + 8 * hi]);
    short8v b1 = *reinterpret_cast<const short8v*>(&wlvb[(16 * t + lo) * 64 + 32 + 8 * hi]);
    accU[t] = __builtin_amdgcn_mfma_f32_16x16x32_bf16(au[0], b0, accU[t], 0, 0, 0);
    accU[t] = __builtin_amdgcn_mfma_f32_16x16x32_bf16(au[1], b1, accU[t], 0, 0, 0);
  }
  // sc einsum: 16 p-chunks
  for (int p = 0; p < 16; ++p) {
    f32x4 cp[4] = {zeroA, zeroA, zeroA, zeroA};
#pragma unroll
    for (int t = 0; t < 4; ++t) {
      const int bbase = (p * 64 + 16 * t + lo) * 64 + 8 * hi;
      short8v b0 = *reinterpret_cast<const short8v*>(&wscb[bbase]);
      short8v b1 = *reinterpret_cast<const short8v*>(&wscb[bbase + 32]);
      cp[t] = __builtin_amdgcn_mfma_f32_16x16x32_bf16(anf[0], b0, cp[t], 0, 0, 0);
      cp[t] = __builtin_amdgcn_mfma_f32_16x16x32_bf16(anf[1], b1, cp[t], 0, 0, 0);
    }
#pragma unroll
    for (int i = 0; i < 4; ++i) {
      float nav = nal[(16 * w + 4 * hi + i) * 17 + p];
#pragma unroll
      for (int t = 0; t < 4; ++t) accS[t][i] = fmaf(nav, cp[t][i], accS[t][i]);
    }
  }
  // write out
#pragma unroll
  for (int i = 0; i < 4; ++i) {
    int n = nb + 16 * w + 4 * hi + i;
    if (n < NN) {
      float s = sl[16 * w + 4 * hi + i];
#pragma unroll
      for (int t = 0; t < 4; ++t) {
        out[n * 64 + 16 * t + lo] = fmaf(s, accU[t][i], accS[t][i]);
      }
    }
  }
}

extern "C" void kernel_launch(void* const* d_in, const int* in_sizes, int n_in,
                              void* d_out, int out_size, void* d_ws, size_t ws_size,
                              hipStream_t stream) {
  const float* nf   = (const float*)d_in[0];
  const float* na   = (const float*)d_in[1];
  const float* eb   = (const float*)d_in[2];
  const float* ea   = (const float*)d_in[3];
  const float* pos  = (const float*)d_in[4];
  const int*   esrc = (const int*)d_in[5];
  const int*   edst = (const int*)d_in[6];
  const float* Wq   = (const float*)d_in[7];
  const float* W1k  = (const float*)d_in[8];
  const float* W2k  = (const float*)d_in[9];
  const float* W1v  = (const float*)d_in[10];
  const float* W2v  = (const float*)d_in[11];
  const float* Wlk  = (const float*)d_in[12];
  const float* Wlv  = (const float*)d_in[13];
  const float* Wdot = (const float*)d_in[14];
  const float* Wsc  = (const float*)d_in[15];
  float* out = (float*)d_out;

  float* wsf = (float*)d_ws;
  float* z     = wsf;
  float* U     = wsf + 65536;
  int*   cnt   = (int*)(wsf + 3265536);
  int*   start = (int*)(wsf + 3315712);
  int*   cur   = (int*)(wsf + 3365888);
  int*   bsum  = (int*)(wsf + 3416064);
  float* tq    = wsf + 3416320;
  float* M     = wsf + 6616320;
  unsigned short* w2kT = (unsigned short*)(wsf + 6620416);
  unsigned short* w2vT = (unsigned short*)(wsf + 6621440);
  unsigned short* wlvb = (unsigned short*)(wsf + 6622464);
  unsigned short* wscb = (unsigned short*)(wsf + 6624512);
  int*   perm  = (int*)(wsf + 6657280);

  // zero z + U + cnt (contiguous)
  hipMemsetAsync(z, 0, (size_t)(3265536 + NPAD) * sizeof(float), stream);

  fold_kernel<<<1, 256, 0, stream>>>(Wq, Wdot, Wlk, W2k, W2v, Wlv, M, w2kT, w2vT, wlvb);
  prep_wsc<<<256, 256, 0, stream>>>(Wsc, wscb);
  hist_kernel<<<EE / 256, 256, 0, stream>>>(edst, cnt);
  scanA_kernel<<<NPAD / 256, 256, 0, stream>>>(cnt, start, bsum);
  scanB_kernel<<<1, 256, 0, stream>>>(bsum);
  scanC_kernel<<<NPAD / 256, 256, 0, stream>>>(start, bsum, cur);
  tq_kernel<<<(NN + 63) / 64, 256, 0, stream>>>(nf, M, tq);
  scatter_kernel<<<EE / 256, 256, 0, stream>>>(edst, cur, perm);
  edge_kernel<<<EE / 64, 256, 0, stream>>>(nf, ea, pos, esrc, edst, eb, W1k, W1v,
                                           tq, w2kT, w2vT, perm, z, U);
  final_kernel<<<(NN + 63) / 64, 256, 0, stream>>>(nf, na, U, z, wscb, wlvb, out);
}

// Round 4
// 350.935 us; speedup vs baseline: 1.3411x; 1.3411x over previous
//
#include <hip/hip_runtime.h>
#include <math.h>

#define NN 50000
#define EE 800000
#define NPAD 50176   // 196*256
#define CPAD 66

typedef __attribute__((ext_vector_type(8))) short short8v;
typedef __attribute__((ext_vector_type(4))) float f32x4;

static __device__ __forceinline__ short bf16r(float x) {
  union { float f; unsigned u; } v; v.f = x;
  unsigned r = v.u + 0x7FFFu + ((v.u >> 16) & 1u);
  return (short)(r >> 16);
}
static __device__ __forceinline__ float bf2f(unsigned u) {
  union { unsigned u; float f; } v; v.u = u << 16;
  return v.f;
}

// ws layout (float offsets):
//   z     @ 0            65536
//   U     @ 65536        3,200,000
//   cnt   @ 3,265,536    50176 (int)
//   start @ 3,315,712    50176 (int)
//   cur   @ 3,365,888    50176 (int)
//   bsum  @ 3,416,064    256   (int)
//   tq    @ 3,416,320    3,200,000
//   M     @ 6,616,320    4096
//   w2kT  @ 6,620,416    1024 (2048 bf16)
//   w2vT  @ 6,621,440    1024
//   Wlvb  @ 6,622,464    2048 (4096 bf16)
//   Wscb  @ 6,624,512    32768 (65536 bf16)
//   ssrc  @ 6,657,280    800000 (int)
//   sdst  @ 7,457,280    800000 (int)
//   scl   @ 8,257,280    800000 (float)
//   sea   @ 9,057,280    3,200,000 (float4/edge)
//   hwb   @ 12,257,280   6,400,000 (16 bf16/edge)
//   end 18,657,280 floats = 74.6 MB

// ---------- fold: M = (W_q@W_dot)@W_lin_k^T ; W2{k,v}->bf16 frag layout; Wlv->bf16 [o][c] ----------
__global__ __launch_bounds__(256) void fold_kernel(
    const float* __restrict__ Wq, const float* __restrict__ Wdot,
    const float* __restrict__ Wlk, const float* __restrict__ W2k,
    const float* __restrict__ W2v, const float* __restrict__ Wlv,
    float* __restrict__ M, unsigned short* __restrict__ w2kT,
    unsigned short* __restrict__ w2vT, unsigned short* __restrict__ wlvb)
{
  __shared__ float tmp[2048];
  const int tid = threadIdx.x;
#pragma unroll
  for (int r = 0; r < 8; ++r) {
    int idx = tid + r * 256;
    int cin = idx >> 5, d = idx & 31;
    float a = 0.f;
    for (int j = 0; j < 32; ++j) a = fmaf(Wq[cin * 32 + j], Wdot[j * 32 + d], a);
    tmp[idx] = a;
  }
  __syncthreads();
#pragma unroll
  for (int r = 0; r < 16; ++r) {
    int idx = tid + r * 256;
    int cin = idx >> 6, c = idx & 63;
    float a = 0.f;
    for (int d = 0; d < 32; ++d) a = fmaf(tmp[cin * 32 + d], Wlk[c * 32 + d], a);
    M[idx] = a;
  }
#pragma unroll
  for (int r = 0; r < 8; ++r) {
    int idx = tid + r * 256;
    int c = idx >> 5, k = idx & 31, h = k >> 2, a = k & 3;
    w2kT[idx] = (unsigned short)bf16r(W2k[h * 256 + c * 4 + a]);
    w2vT[idx] = (unsigned short)bf16r(W2v[h * 256 + c * 4 + a]);
  }
#pragma unroll
  for (int r = 0; r < 16; ++r) {
    int idx = tid + r * 256;
    int o = idx >> 6, c = idx & 63;
    wlvb[idx] = (unsigned short)bf16r(Wlv[c * 64 + o]);
  }
}

// ---------- Wscb[(p*64+o)*64+c] = bf16(Wsc[c*1024 + p*64 + o]) ----------
__global__ __launch_bounds__(256) void prep_wsc(
    const float* __restrict__ Wsc, unsigned short* __restrict__ wscb)
{
  int w = blockIdx.x * 256 + threadIdx.x;
  int c = w & 63, o = (w >> 6) & 63, p = w >> 12;
  wscb[w] = (unsigned short)bf16r(Wsc[c * 1024 + p * 64 + o]);
}

// ---------- counting sort ----------
__global__ __launch_bounds__(256) void hist_kernel(
    const int* __restrict__ edst, int* __restrict__ cnt)
{
  int e = blockIdx.x * 256 + threadIdx.x;
  atomicAdd(&cnt[edst[e]], 1);
}

__global__ __launch_bounds__(256) void scanA_kernel(
    const int* __restrict__ cnt, int* __restrict__ start, int* __restrict__ bsum)
{
  __shared__ int s[256];
  const int tid = threadIdx.x;
  const int i = blockIdx.x * 256 + tid;
  int v = cnt[i];
  s[tid] = v;
  __syncthreads();
  for (int off = 1; off < 256; off <<= 1) {
    int t = (tid >= off) ? s[tid - off] : 0;
    __syncthreads();
    s[tid] += t;
    __syncthreads();
  }
  start[i] = s[tid] - v;
  if (tid == 255) bsum[blockIdx.x] = s[255];
}

__global__ __launch_bounds__(256) void scanB_kernel(int* __restrict__ bsum)
{
  __shared__ int s[256];
  const int tid = threadIdx.x;
  int v = (tid < 196) ? bsum[tid] : 0;
  s[tid] = v;
  __syncthreads();
  for (int off = 1; off < 256; off <<= 1) {
    int t = (tid >= off) ? s[tid - off] : 0;
    __syncthreads();
    s[tid] += t;
    __syncthreads();
  }
  if (tid < 196) bsum[tid] = s[tid] - v;
}

__global__ __launch_bounds__(256) void scanC_kernel(
    int* __restrict__ start, const int* __restrict__ bsum, int* __restrict__ cur)
{
  const int i = blockIdx.x * 256 + threadIdx.x;
  int sv = start[i] + bsum[blockIdx.x];
  start[i] = sv;
  cur[i] = sv;
}

// ---------- fused scatter: sort payload + cutoff + radial MLP, all written at rank r ----------
__global__ __launch_bounds__(256) void scatter_fused(
    const int* __restrict__ esrc, const int* __restrict__ edst,
    const float* __restrict__ ea, const float* __restrict__ eb,
    const float* __restrict__ pos, const float* __restrict__ W1k,
    const float* __restrict__ W1v, int* __restrict__ cur,
    int* __restrict__ ssrc, int* __restrict__ sdst, float* __restrict__ scl,
    float4* __restrict__ sea, unsigned short* __restrict__ hwb)
{
  int e = blockIdx.x * 256 + threadIdx.x;
  int s = esrc[e], d = edst[e];
  int r = atomicAdd(&cur[d], 1);
  ssrc[r] = s;
  sdst[r] = d;
  sea[r] = reinterpret_cast<const float4*>(ea)[e];
  float dx = pos[d * 3 + 0] - pos[s * 3 + 0];
  float dy = pos[d * 3 + 1] - pos[s * 3 + 1];
  float dz = pos[d * 3 + 2] - pos[s * 3 + 2];
  float len = sqrtf(fmaf(dx, dx, fmaf(dy, dy, dz * dz)));
  float arg = 10.f - 2.f * len;
  scl[r] = (arg > 0.f) ? __expf(-1.f / arg) : 0.f;
  // radial MLP (f32), output bf16 [hk0..7, hv0..7]
  const float4* eb4 = reinterpret_cast<const float4*>(eb);
  float4 q0 = eb4[e * 4 + 0], q1 = eb4[e * 4 + 1],
         q2 = eb4[e * 4 + 2], q3 = eb4[e * 4 + 3];
  float ebv[16] = {q0.x, q0.y, q0.z, q0.w, q1.x, q1.y, q1.z, q1.w,
                   q2.x, q2.y, q2.z, q2.w, q3.x, q3.y, q3.z, q3.w};
  float h[16];
#pragma unroll
  for (int j = 0; j < 16; ++j) h[j] = 0.f;
#pragma unroll
  for (int b = 0; b < 16; ++b) {
    float x = ebv[b];
#pragma unroll
    for (int j = 0; j < 8; ++j) {
      h[j]     = fmaf(x, W1k[b * 8 + j], h[j]);
      h[8 + j] = fmaf(x, W1v[b * 8 + j], h[8 + j]);
    }
  }
  short8v pk, pv;
#pragma unroll
  for (int j = 0; j < 8; ++j) {
    float a = h[j]     / (1.f + __expf(-h[j]));
    float b = h[8 + j] / (1.f + __expf(-h[8 + j]));
    pk[j] = bf16r(a);
    pv[j] = bf16r(b);
  }
  *reinterpret_cast<short8v*>(&hwb[(size_t)r * 16]) = pk;
  *reinterpret_cast<short8v*>(&hwb[(size_t)r * 16 + 8]) = pv;
}

// ---------- tq = nf @ M ----------
__global__ __launch_bounds__(256) void tq_kernel(
    const float* __restrict__ nf, const float* __restrict__ M, float* __restrict__ tq)
{
  __shared__ float Ml[4096];
  __shared__ float nfl[64 * 68];
  const int tid = threadIdx.x;
  const int base = blockIdx.x * 64;
#pragma unroll
  for (int r = 0; r < 4; ++r) {
    int idx = tid + r * 256;
    reinterpret_cast<float4*>(Ml)[idx] = reinterpret_cast<const float4*>(M)[idx];
  }
#pragma unroll
  for (int r = 0; r < 4; ++r) {
    int idx = tid + r * 256;
    int row = idx >> 4, c4 = idx & 15;
    float4 v = make_float4(0.f, 0.f, 0.f, 0.f);
    if (base + row < NN) v = reinterpret_cast<const float4*>(nf)[(base + row) * 16 + c4];
    *reinterpret_cast<float4*>(&nfl[row * 68 + c4 * 4]) = v;
  }
  __syncthreads();
  const int to = tid & 15, tn = tid >> 4;
  float4 acc[4] = {make_float4(0,0,0,0), make_float4(0,0,0,0),
                   make_float4(0,0,0,0), make_float4(0,0,0,0)};
  for (int c = 0; c < 64; ++c) {
    float4 m = reinterpret_cast<const float4*>(Ml)[c * 16 + to];
#pragma unroll
    for (int i = 0; i < 4; ++i) {
      float x = nfl[(tn * 4 + i) * 68 + c];
      acc[i].x = fmaf(x, m.x, acc[i].x);
      acc[i].y = fmaf(x, m.y, acc[i].y);
      acc[i].z = fmaf(x, m.z, acc[i].z);
      acc[i].w = fmaf(x, m.w, acc[i].w);
    }
  }
#pragma unroll
  for (int i = 0; i < 4; ++i) {
    int n = base + tn * 4 + i;
    if (n < NN) reinterpret_cast<float4*>(tq)[n * 16 + to] = acc[i];
  }
}

// ---------- edge pass: 64 sorted edges/block, zero indirection, segmented-reduce epilogue ----------
__global__ __launch_bounds__(256) void edge_kernel(
    const float* __restrict__ nf, const float* __restrict__ tq,
    const int* __restrict__ ssrc, const int* __restrict__ sdst,
    const float* __restrict__ scl, const float4* __restrict__ sea,
    const unsigned short* __restrict__ hwb,
    const unsigned short* __restrict__ w2kT, const unsigned short* __restrict__ w2vT,
    float* __restrict__ z, float* __restrict__ U)
{
  __shared__ float ys[64 * CPAD];   // x_src * tq_dst; later reused as msg
  __shared__ float xs[64 * CPAD];   // x_src
  __shared__ int   ed[64];
  __shared__ float cl[64];
  __shared__ float evs[64];
  const int tid  = threadIdx.x;
  const int lane = tid & 63;
  const int lo = lane & 15, hi = lane >> 4;
  const int w = tid >> 6;
  const int sb = blockIdx.x * 64;
  const int row = 16 * w + lo;

  // B fragments (loop-invariant)
  short8v bk[4], bv[4];
#pragma unroll
  for (int t = 0; t < 4; ++t) {
    bk[t] = *reinterpret_cast<const short8v*>(&w2kT[(16 * t + lo) * 32 + hi * 8]);
    bv[t] = *reinterpret_cast<const short8v*>(&w2vT[(16 * t + lo) * 32 + hi * 8]);
  }
  // A-fragment inputs (all linear loads)
  const unsigned short* hwp = &hwb[(size_t)(sb + row) * 16];
  unsigned k01 = *reinterpret_cast<const unsigned*>(&hwp[2 * hi]);
  unsigned v01 = *reinterpret_cast<const unsigned*>(&hwp[8 + 2 * hi]);
  float4 a4 = sea[sb + row];

  if (tid < 64) {
    ed[tid] = sdst[sb + tid];
    cl[tid] = scl[sb + tid];
  }
  // stage x_src and x_src*tq_dst
#pragma unroll
  for (int r = 0; r < 4; ++r) {
    int idx = tid + r * 256;
    int e = idx >> 4, c4 = idx & 15;
    int s = ssrc[sb + e], d = sdst[sb + e];
    float4 xv = reinterpret_cast<const float4*>(nf)[s * 16 + c4];
    float4 tv = reinterpret_cast<const float4*>(tq)[d * 16 + c4];
    float* xp = &xs[e * CPAD + c4 * 4];
    xp[0] = xv.x; xp[1] = xv.y; xp[2] = xv.z; xp[3] = xv.w;
    float* yp = &ys[e * CPAD + c4 * 4];
    yp[0] = xv.x * tv.x; yp[1] = xv.y * tv.y; yp[2] = xv.z * tv.z; yp[3] = xv.w * tv.w;
  }

  // build A fragments while staging is in flight
  float hk0 = bf2f(k01 & 0xffffu), hk1 = bf2f(k01 >> 16);
  float hv0 = bf2f(v01 & 0xffffu), hv1 = bf2f(v01 >> 16);
  short8v ak, av;
  ak[0] = bf16r(hk0 * a4.x); ak[1] = bf16r(hk0 * a4.y);
  ak[2] = bf16r(hk0 * a4.z); ak[3] = bf16r(hk0 * a4.w);
  ak[4] = bf16r(hk1 * a4.x); ak[5] = bf16r(hk1 * a4.y);
  ak[6] = bf16r(hk1 * a4.z); ak[7] = bf16r(hk1 * a4.w);
  av[0] = bf16r(hv0 * a4.x); av[1] = bf16r(hv0 * a4.y);
  av[2] = bf16r(hv0 * a4.z); av[3] = bf16r(hv0 * a4.w);
  av[4] = bf16r(hv1 * a4.x); av[5] = bf16r(hv1 * a4.y);
  av[6] = bf16r(hv1 * a4.z); av[7] = bf16r(hv1 * a4.w);

  __syncthreads();

  f32x4 zero = {0.f, 0.f, 0.f, 0.f};
  f32x4 ack[4], acv[4];
#pragma unroll
  for (int t = 0; t < 4; ++t) {
    ack[t] = __builtin_amdgcn_mfma_f32_16x16x32_bf16(ak, bk[t], zero, 0, 0, 0);
    acv[t] = __builtin_amdgcn_mfma_f32_16x16x32_bf16(av, bv[t], zero, 0, 0, 0);
  }

  // score per C-row (edge erow+i)
  const int erow = 16 * w + 4 * hi;
  float p0, p1, p2, p3;
  {
    const float* y0 = &ys[(erow + 0) * CPAD + lo];
    const float* y1 = &ys[(erow + 1) * CPAD + lo];
    const float* y2 = &ys[(erow + 2) * CPAD + lo];
    const float* y3 = &ys[(erow + 3) * CPAD + lo];
    p0 = y0[0]*ack[0][0] + y0[16]*ack[1][0] + y0[32]*ack[2][0] + y0[48]*ack[3][0];
    p1 = y1[0]*ack[0][1] + y1[16]*ack[1][1] + y1[32]*ack[2][1] + y1[48]*ack[3][1];
    p2 = y2[0]*ack[0][2] + y2[16]*ack[1][2] + y2[32]*ack[2][2] + y2[48]*ack[3][2];
    p3 = y3[0]*ack[0][3] + y3[16]*ack[1][3] + y3[32]*ack[2][3] + y3[48]*ack[3][3];
  }
#pragma unroll
  for (int off = 1; off < 16; off <<= 1) {
    p0 += __shfl_xor(p0, off);
    p1 += __shfl_xor(p1, off);
    p2 += __shfl_xor(p2, off);
    p3 += __shfl_xor(p3, off);
  }
  float ev0 = cl[erow + 0] * __expf(0.5f * p0);
  float ev1 = cl[erow + 1] * __expf(0.5f * p1);
  float ev2 = cl[erow + 2] * __expf(0.5f * p2);
  float ev3 = cl[erow + 3] * __expf(0.5f * p3);
  float se0 = sqrtf(ev0), se1 = sqrtf(ev1), se2 = sqrtf(ev2), se3 = sqrtf(ev3);
  if (lo < 4) {
    float ev = (lo == 0) ? ev0 : (lo == 1) ? ev1 : (lo == 2) ? ev2 : ev3;
    evs[erow + lo] = ev;
  }
  // msg[e][c] = se * x_src[c] * sv[c]
#pragma unroll
  for (int i = 0; i < 4; ++i) {
    const float se = (i == 0) ? se0 : (i == 1) ? se1 : (i == 2) ? se2 : se3;
    float* mr = &ys[(erow + i) * CPAD + lo];
    const float* xr = &xs[(erow + i) * CPAD + lo];
#pragma unroll
    for (int t = 0; t < 4; ++t) {
      mr[16 * t] = se * xr[16 * t] * acv[t][i];
    }
  }
  // segmented reduce: wave w walks strip [16w,16w+16), lane = channel
  {
    const int c = lane;
    float acc = 0.f, evacc = 0.f;
    int prev = ed[16 * w];
    for (int r = 16 * w; r < 16 * w + 16; ++r) {
      int d = ed[r];
      if (d != prev) {
        unsafeAtomicAdd(&U[prev * 64 + c], acc);
        if (c == 0) unsafeAtomicAdd(&z[prev], evacc);
        acc = 0.f; evacc = 0.f; prev = d;
      }
      acc += ys[r * CPAD + c];
      if (c == 0) evacc += evs[r];
    }
    unsafeAtomicAdd(&U[prev * 64 + c], acc);
    if (c == 0) unsafeAtomicAdd(&z[prev], evacc);
  }
}

// ---------- final (MFMA): out = s*(U@Wlv) + einsum(nf,na,Wsc) ----------
__global__ __launch_bounds__(256) void final_kernel(
    const float* __restrict__ nf, const float* __restrict__ na,
    const float* __restrict__ U, const float* __restrict__ z,
    const unsigned short* __restrict__ wscb, const unsigned short* __restrict__ wlvb,
    float* __restrict__ out)
{
  __shared__ float nfl[64 * 68];
  __shared__ float Ul[64 * 68];
  __shared__ float nal[64 * 17];
  __shared__ float sl[64];
  const int tid = threadIdx.x;
  const int lane = tid & 63;
  const int lo = lane & 15, hi = lane >> 4;
  const int w = tid >> 6;
  const int nb = blockIdx.x * 64;

#pragma unroll
  for (int r = 0; r < 4; ++r) {
    int idx = tid + r * 256;
    int row = idx >> 4, c4 = idx & 15;
    int n = nb + row; if (n >= NN) n = NN - 1;
    float4 v = reinterpret_cast<const float4*>(nf)[n * 16 + c4];
    *reinterpret_cast<float4*>(&nfl[row * 68 + c4 * 4]) = v;
    float4 u = reinterpret_cast<const float4*>(U)[n * 16 + c4];
    *reinterpret_cast<float4*>(&Ul[row * 68 + c4 * 4]) = u;
  }
#pragma unroll
  for (int r = 0; r < 4; ++r) {
    int idx = tid + r * 256;
    int row = idx >> 4, p = idx & 15;
    int n = nb + row; if (n >= NN) n = NN - 1;
    nal[row * 17 + p] = na[n * 16 + p];
  }
  if (tid < 64) {
    int n = nb + tid; if (n >= NN) n = NN - 1;
    float zz = z[n];
    sl[tid] = (zz > 0.f) ? 0.5f * rsqrtf(zz) : 0.f;
  }
  __syncthreads();

  const int row = 16 * w + lo;
  short8v anf[2], au[2];
#pragma unroll
  for (int kk = 0; kk < 2; ++kk) {
#pragma unroll
    for (int j = 0; j < 8; ++j) {
      anf[kk][j] = bf16r(nfl[row * 68 + 32 * kk + 8 * hi + j]);
      au[kk][j]  = bf16r(Ul[row * 68 + 32 * kk + 8 * hi + j]);
    }
  }

  f32x4 zeroA = {0.f, 0.f, 0.f, 0.f};
  f32x4 accS[4] = {zeroA, zeroA, zeroA, zeroA};
  f32x4 accU[4] = {zeroA, zeroA, zeroA, zeroA};

  // U @ Wlv
#pragma unroll
  for (int t = 0; t < 4; ++t) {
    short8v b0 = *reinterpret_cast<const short8v*>(&wlvb[(16 * t + lo) * 64 + 8 * hi]);
    short8v b1 = *reinterpret_cast<const short8v*>(&wlvb[(16 * t + lo) * 64 + 32 + 8 * hi]);
    accU[t] = __builtin_amdgcn_mfma_f32_16x16x32_bf16(au[0], b0, accU[t], 0, 0, 0);
    accU[t] = __builtin_amdgcn_mfma_f32_16x16x32_bf16(au[1], b1, accU[t], 0, 0, 0);
  }
  // sc einsum: 16 p-chunks
  for (int p = 0; p < 16; ++p) {
    f32x4 cp[4] = {zeroA, zeroA, zeroA, zeroA};
#pragma unroll
    for (int t = 0; t < 4; ++t) {
      const int bbase = (p * 64 + 16 * t + lo) * 64 + 8 * hi;
      short8v b0 = *reinterpret_cast<const short8v*>(&wscb[bbase]);
      short8v b1 = *reinterpret_cast<const short8v*>(&wscb[bbase + 32]);
      cp[t] = __builtin_amdgcn_mfma_f32_16x16x32_bf16(anf[0], b0, cp[t], 0, 0, 0);
      cp[t] = __builtin_amdgcn_mfma_f32_16x16x32_bf16(anf[1], b1, cp[t], 0, 0, 0);
    }
#pragma unroll
    for (int i = 0; i < 4; ++i) {
      float nav = nal[(16 * w + 4 * hi + i) * 17 + p];
#pragma unroll
      for (int t = 0; t < 4; ++t) accS[t][i] = fmaf(nav, cp[t][i], accS[t][i]);
    }
  }
  // write out
#pragma unroll
  for (int i = 0; i < 4; ++i) {
    int n = nb + 16 * w + 4 * hi + i;
    if (n < NN) {
      float s = sl[16 * w + 4 * hi + i];
#pragma unroll
      for (int t = 0; t < 4; ++t) {
        out[n * 64 + 16 * t + lo] = fmaf(s, accU[t][i], accS[t][i]);
      }
    }
  }
}

extern "C" void kernel_launch(void* const* d_in, const int* in_sizes, int n_in,
                              void* d_out, int out_size, void* d_ws, size_t ws_size,
                              hipStream_t stream) {
  const float* nf   = (const float*)d_in[0];
  const float* na   = (const float*)d_in[1];
  const float* eb   = (const float*)d_in[2];
  const float* ea   = (const float*)d_in[3];
  const float* pos  = (const float*)d_in[4];
  const int*   esrc = (const int*)d_in[5];
  const int*   edst = (const int*)d_in[6];
  const float* Wq   = (const float*)d_in[7];
  const float* W1k  = (const float*)d_in[8];
  const float* W2k  = (const float*)d_in[9];
  const float* W1v  = (const float*)d_in[10];
  const float* W2v  = (const float*)d_in[11];
  const float* Wlk  = (const float*)d_in[12];
  const float* Wlv  = (const float*)d_in[13];
  const float* Wdot = (const float*)d_in[14];
  const float* Wsc  = (const float*)d_in[15];
  float* out = (float*)d_out;

  float* wsf = (float*)d_ws;
  float* z     = wsf;
  float* U     = wsf + 65536;
  int*   cnt   = (int*)(wsf + 3265536);
  int*   start = (int*)(wsf + 3315712);
  int*   cur   = (int*)(wsf + 3365888);
  int*   bsum  = (int*)(wsf + 3416064);
  float* tq    = wsf + 3416320;
  float* M     = wsf + 6616320;
  unsigned short* w2kT = (unsigned short*)(wsf + 6620416);
  unsigned short* w2vT = (unsigned short*)(wsf + 6621440);
  unsigned short* wlvb = (unsigned short*)(wsf + 6622464);
  unsigned short* wscb = (unsigned short*)(wsf + 6624512);
  int*   ssrc  = (int*)(wsf + 6657280);
  int*   sdst  = (int*)(wsf + 7457280);
  float* scl   = wsf + 8257280;
  float4* sea  = (float4*)(wsf + 9057280);
  unsigned short* hwb = (unsigned short*)(wsf + 12257280);

  // zero z + U + cnt (contiguous)
  hipMemsetAsync(z, 0, (size_t)(3265536 + NPAD) * sizeof(float), stream);

  fold_kernel<<<1, 256, 0, stream>>>(Wq, Wdot, Wlk, W2k, W2v, Wlv, M, w2kT, w2vT, wlvb);
  prep_wsc<<<256, 256, 0, stream>>>(Wsc, wscb);
  hist_kernel<<<EE / 256, 256, 0, stream>>>(edst, cnt);
  scanA_kernel<<<NPAD / 256, 256, 0, stream>>>(cnt, start, bsum);
  scanB_kernel<<<1, 256, 0, stream>>>(bsum);
  scanC_kernel<<<NPAD / 256, 256, 0, stream>>>(start, bsum, cur);
  scatter_fused<<<EE / 256, 256, 0, stream>>>(esrc, edst, ea, eb, pos, W1k, W1v,
                                              cur, ssrc, sdst, scl, sea, hwb);
  tq_kernel<<<(NN + 63) / 64, 256, 0, stream>>>(nf, M, tq);
  edge_kernel<<<EE / 64, 256, 0, stream>>>(nf, tq, ssrc, sdst, scl, sea, hwb,
                                           w2kT, w2vT, z, U);
  final_kernel<<<(NN + 63) / 64, 256, 0, stream>>>(nf, na, U, z, wscb, wlvb, out);
}

// Round 5
// 329.988 us; speedup vs baseline: 1.4263x; 1.0635x over previous
//
#include <hip/hip_runtime.h>
#include <math.h>

#define NN 50000
#define EE 800000
#define NPAD 50176   // 196*256
#define CPAD 66

typedef __attribute__((ext_vector_type(8))) short short8v;
typedef __attribute__((ext_vector_type(4))) float f32x4;

static __device__ __forceinline__ short bf16r(float x) {
  union { float f; unsigned u; } v; v.f = x;
  unsigned r = v.u + 0x7FFFu + ((v.u >> 16) & 1u);
  return (short)(r >> 16);
}
static __device__ __forceinline__ float bf2f(unsigned u) {
  union { unsigned u; float f; } v; v.u = u << 16;
  return v.f;
}
static __device__ __forceinline__ unsigned pk2(float a, float b) {
  return (unsigned)(unsigned short)bf16r(a) | ((unsigned)(unsigned short)bf16r(b) << 16);
}

// ws layout (float offsets), total 19,254,272 floats = 77.017 MB:
//   z     @ 0           50,176
//   U     @ 50,176      3,200,000   [overlays: cur @50,176 (50,176 int), bsum @100,352 (256), M @100,608 (4,096)]
//   tq    @ 3,250,176   3,200,000   [overlay after edge: wscb (32,768 floats = 65,536 bf16)]
//   w2kT  @ 6,450,176   1,024
//   w2vT  @ 6,451,200   1,024
//   wlvb  @ 6,452,224   2,048
//   rec   @ 6,454,272   12,800,000  (16 words = 64 B per edge)
//
// rec word layout: [0]=src [1]=dst [2]=cl [3]=pad [4..7]=ea f32x4
//                  [8..11]=hk 8xbf16  [12..15]=hv 8xbf16
//
// launch order: fold -> tq -> memset(cur+bsum) -> hist -> scanA/B/C -> scatter
//               -> memset(z+U) -> edge -> prep_wsc -> final

// ---------- fold: M = (W_q@W_dot)@W_lin_k^T ; W2{k,v}->bf16 frag layout; Wlv->bf16 [o][c] ----------
__global__ __launch_bounds__(256) void fold_kernel(
    const float* __restrict__ Wq, const float* __restrict__ Wdot,
    const float* __restrict__ Wlk, const float* __restrict__ W2k,
    const float* __restrict__ W2v, const float* __restrict__ Wlv,
    float* __restrict__ M, unsigned short* __restrict__ w2kT,
    unsigned short* __restrict__ w2vT, unsigned short* __restrict__ wlvb)
{
  __shared__ float tmp[2048];
  const int tid = threadIdx.x;
#pragma unroll
  for (int r = 0; r < 8; ++r) {
    int idx = tid + r * 256;
    int cin = idx >> 5, d = idx & 31;
    float a = 0.f;
    for (int j = 0; j < 32; ++j) a = fmaf(Wq[cin * 32 + j], Wdot[j * 32 + d], a);
    tmp[idx] = a;
  }
  __syncthreads();
#pragma unroll
  for (int r = 0; r < 16; ++r) {
    int idx = tid + r * 256;
    int cin = idx >> 6, c = idx & 63;
    float a = 0.f;
    for (int d = 0; d < 32; ++d) a = fmaf(tmp[cin * 32 + d], Wlk[c * 32 + d], a);
    M[idx] = a;
  }
#pragma unroll
  for (int r = 0; r < 8; ++r) {
    int idx = tid + r * 256;
    int c = idx >> 5, k = idx & 31, h = k >> 2, a = k & 3;
    w2kT[idx] = (unsigned short)bf16r(W2k[h * 256 + c * 4 + a]);
    w2vT[idx] = (unsigned short)bf16r(W2v[h * 256 + c * 4 + a]);
  }
#pragma unroll
  for (int r = 0; r < 16; ++r) {
    int idx = tid + r * 256;
    int o = idx >> 6, c = idx & 63;
    wlvb[idx] = (unsigned short)bf16r(Wlv[c * 64 + o]);
  }
}

// ---------- Wscb[(p*64+o)*64+c] = bf16(Wsc[c*1024 + p*64 + o]) ----------
__global__ __launch_bounds__(256) void prep_wsc(
    const float* __restrict__ Wsc, unsigned short* __restrict__ wscb)
{
  int w = blockIdx.x * 256 + threadIdx.x;
  int c = w & 63, o = (w >> 6) & 63, p = w >> 12;
  wscb[w] = (unsigned short)bf16r(Wsc[c * 1024 + p * 64 + o]);
}

// ---------- counting sort (in-place in cur) ----------
__global__ __launch_bounds__(256) void hist_kernel(
    const int* __restrict__ edst, int* __restrict__ cur)
{
  int e = blockIdx.x * 256 + threadIdx.x;
  atomicAdd(&cur[edst[e]], 1);
}

__global__ __launch_bounds__(256) void scanA_kernel(
    int* __restrict__ cur, int* __restrict__ bsum)
{
  __shared__ int s[256];
  const int tid = threadIdx.x;
  const int i = blockIdx.x * 256 + tid;
  int v = cur[i];
  s[tid] = v;
  __syncthreads();
  for (int off = 1; off < 256; off <<= 1) {
    int t = (tid >= off) ? s[tid - off] : 0;
    __syncthreads();
    s[tid] += t;
    __syncthreads();
  }
  cur[i] = s[tid] - v;
  if (tid == 255) bsum[blockIdx.x] = s[255];
}

__global__ __launch_bounds__(256) void scanB_kernel(int* __restrict__ bsum)
{
  __shared__ int s[256];
  const int tid = threadIdx.x;
  int v = (tid < 196) ? bsum[tid] : 0;
  s[tid] = v;
  __syncthreads();
  for (int off = 1; off < 256; off <<= 1) {
    int t = (tid >= off) ? s[tid - off] : 0;
    __syncthreads();
    s[tid] += t;
    __syncthreads();
  }
  if (tid < 196) bsum[tid] = s[tid] - v;
}

__global__ __launch_bounds__(256) void scanC_kernel(
    int* __restrict__ cur, const int* __restrict__ bsum)
{
  const int i = blockIdx.x * 256 + threadIdx.x;
  cur[i] += bsum[blockIdx.x];
}

// ---------- fused scatter: one 64B record per edge at rank r ----------
__global__ __launch_bounds__(256) void scatter_fused(
    const int* __restrict__ esrc, const int* __restrict__ edst,
    const float* __restrict__ ea, const float* __restrict__ eb,
    const float* __restrict__ pos, const float* __restrict__ W1k,
    const float* __restrict__ W1v, int* __restrict__ cur,
    float* __restrict__ rec)
{
  int e = blockIdx.x * 256 + threadIdx.x;
  int s = esrc[e], d = edst[e];
  int r = atomicAdd(&cur[d], 1);
  float dx = pos[d * 3 + 0] - pos[s * 3 + 0];
  float dy = pos[d * 3 + 1] - pos[s * 3 + 1];
  float dz = pos[d * 3 + 2] - pos[s * 3 + 2];
  float len = sqrtf(fmaf(dx, dx, fmaf(dy, dy, dz * dz)));
  float arg = 10.f - 2.f * len;
  float cl = (arg > 0.f) ? __expf(-1.f / arg) : 0.f;
  // radial MLP (f32)
  const float4* eb4 = reinterpret_cast<const float4*>(eb);
  float4 q0 = eb4[e * 4 + 0], q1 = eb4[e * 4 + 1],
         q2 = eb4[e * 4 + 2], q3 = eb4[e * 4 + 3];
  float ebv[16] = {q0.x, q0.y, q0.z, q0.w, q1.x, q1.y, q1.z, q1.w,
                   q2.x, q2.y, q2.z, q2.w, q3.x, q3.y, q3.z, q3.w};
  float h[16];
#pragma unroll
  for (int j = 0; j < 16; ++j) h[j] = 0.f;
#pragma unroll
  for (int b = 0; b < 16; ++b) {
    float x = ebv[b];
#pragma unroll
    for (int j = 0; j < 8; ++j) {
      h[j]     = fmaf(x, W1k[b * 8 + j], h[j]);
      h[8 + j] = fmaf(x, W1v[b * 8 + j], h[8 + j]);
    }
  }
#pragma unroll
  for (int j = 0; j < 16; ++j) h[j] = h[j] / (1.f + __expf(-h[j]));  // silu

  float* rp = rec + (size_t)r * 16;
  float4 w0;
  w0.x = __int_as_float(s); w0.y = __int_as_float(d); w0.z = cl; w0.w = 0.f;
  reinterpret_cast<float4*>(rp)[0] = w0;
  reinterpret_cast<float4*>(rp)[1] = reinterpret_cast<const float4*>(ea)[e];
  float4 w2, w3;
  w2.x = __uint_as_float(pk2(h[0], h[1]));
  w2.y = __uint_as_float(pk2(h[2], h[3]));
  w2.z = __uint_as_float(pk2(h[4], h[5]));
  w2.w = __uint_as_float(pk2(h[6], h[7]));
  w3.x = __uint_as_float(pk2(h[8], h[9]));
  w3.y = __uint_as_float(pk2(h[10], h[11]));
  w3.z = __uint_as_float(pk2(h[12], h[13]));
  w3.w = __uint_as_float(pk2(h[14], h[15]));
  reinterpret_cast<float4*>(rp)[2] = w2;
  reinterpret_cast<float4*>(rp)[3] = w3;
}

// ---------- tq = nf @ M ----------
__global__ __launch_bounds__(256) void tq_kernel(
    const float* __restrict__ nf, const float* __restrict__ M, float* __restrict__ tq)
{
  __shared__ float Ml[4096];
  __shared__ float nfl[64 * 68];
  const int tid = threadIdx.x;
  const int base = blockIdx.x * 64;
#pragma unroll
  for (int r = 0; r < 4; ++r) {
    int idx = tid + r * 256;
    reinterpret_cast<float4*>(Ml)[idx] = reinterpret_cast<const float4*>(M)[idx];
  }
#pragma unroll
  for (int r = 0; r < 4; ++r) {
    int idx = tid + r * 256;
    int row = idx >> 4, c4 = idx & 15;
    float4 v = make_float4(0.f, 0.f, 0.f, 0.f);
    if (base + row < NN) v = reinterpret_cast<const float4*>(nf)[(base + row) * 16 + c4];
    *reinterpret_cast<float4*>(&nfl[row * 68 + c4 * 4]) = v;
  }
  __syncthreads();
  const int to = tid & 15, tn = tid >> 4;
  float4 acc[4] = {make_float4(0,0,0,0), make_float4(0,0,0,0),
                   make_float4(0,0,0,0), make_float4(0,0,0,0)};
  for (int c = 0; c < 64; ++c) {
    float4 m = reinterpret_cast<const float4*>(Ml)[c * 16 + to];
#pragma unroll
    for (int i = 0; i < 4; ++i) {
      float x = nfl[(tn * 4 + i) * 68 + c];
      acc[i].x = fmaf(x, m.x, acc[i].x);
      acc[i].y = fmaf(x, m.y, acc[i].y);
      acc[i].z = fmaf(x, m.z, acc[i].z);
      acc[i].w = fmaf(x, m.w, acc[i].w);
    }
  }
#pragma unroll
  for (int i = 0; i < 4; ++i) {
    int n = base + tn * 4 + i;
    if (n < NN) reinterpret_cast<float4*>(tq)[n * 16 + to] = acc[i];
  }
}

// ---------- edge pass: 64 sorted edges/block from 64B records, segmented-reduce epilogue ----------
__global__ __launch_bounds__(256) void edge_kernel(
    const float* __restrict__ nf, const float* __restrict__ tq,
    const float* __restrict__ rec,
    const unsigned short* __restrict__ w2kT, const unsigned short* __restrict__ w2vT,
    float* __restrict__ z, float* __restrict__ U)
{
  __shared__ float ys[64 * CPAD];   // x_src * tq_dst; later reused as msg
  __shared__ float xs[64 * CPAD];   // x_src
  __shared__ int   ed[64];
  __shared__ float cl[64];
  __shared__ float evs[64];
  const int tid  = threadIdx.x;
  const int lane = tid & 63;
  const int lo = lane & 15, hi = lane >> 4;
  const int w = tid >> 6;
  const int sb = blockIdx.x * 64;
  const int row = 16 * w + lo;

  // B fragments (loop-invariant)
  short8v bk[4], bv[4];
#pragma unroll
  for (int t = 0; t < 4; ++t) {
    bk[t] = *reinterpret_cast<const short8v*>(&w2kT[(16 * t + lo) * 32 + hi * 8]);
    bv[t] = *reinterpret_cast<const short8v*>(&w2vT[(16 * t + lo) * 32 + hi * 8]);
  }
  // A-fragment inputs from this lane's record
  const unsigned* ru = reinterpret_cast<const unsigned*>(rec);
  const size_t rb = (size_t)(sb + row) * 16;
  unsigned k01 = ru[rb + 8 + hi];
  unsigned v01 = ru[rb + 12 + hi];
  float4 a4 = *reinterpret_cast<const float4*>(rec + rb + 4);

  if (tid < 64) {
    const size_t rb2 = (size_t)(sb + tid) * 16;
    ed[tid] = (int)ru[rb2 + 1];
    cl[tid] = rec[rb2 + 2];
  }
  // stage x_src and x_src*tq_dst
#pragma unroll
  for (int r = 0; r < 4; ++r) {
    int idx = tid + r * 256;
    int e = idx >> 4, c4 = idx & 15;
    const size_t rb3 = (size_t)(sb + e) * 16;
    int s = (int)ru[rb3 + 0];
    int d = (int)ru[rb3 + 1];
    float4 xv = reinterpret_cast<const float4*>(nf)[s * 16 + c4];
    float4 tv = reinterpret_cast<const float4*>(tq)[d * 16 + c4];
    float* xp = &xs[e * CPAD + c4 * 4];
    xp[0] = xv.x; xp[1] = xv.y; xp[2] = xv.z; xp[3] = xv.w;
    float* yp = &ys[e * CPAD + c4 * 4];
    yp[0] = xv.x * tv.x; yp[1] = xv.y * tv.y; yp[2] = xv.z * tv.z; yp[3] = xv.w * tv.w;
  }

  // build A fragments while staging is in flight
  float hk0 = bf2f(k01 & 0xffffu), hk1 = bf2f(k01 >> 16);
  float hv0 = bf2f(v01 & 0xffffu), hv1 = bf2f(v01 >> 16);
  short8v ak, av;
  ak[0] = bf16r(hk0 * a4.x); ak[1] = bf16r(hk0 * a4.y);
  ak[2] = bf16r(hk0 * a4.z); ak[3] = bf16r(hk0 * a4.w);
  ak[4] = bf16r(hk1 * a4.x); ak[5] = bf16r(hk1 * a4.y);
  ak[6] = bf16r(hk1 * a4.z); ak[7] = bf16r(hk1 * a4.w);
  av[0] = bf16r(hv0 * a4.x); av[1] = bf16r(hv0 * a4.y);
  av[2] = bf16r(hv0 * a4.z); av[3] = bf16r(hv0 * a4.w);
  av[4] = bf16r(hv1 * a4.x); av[5] = bf16r(hv1 * a4.y);
  av[6] = bf16r(hv1 * a4.z); av[7] = bf16r(hv1 * a4.w);

  __syncthreads();

  f32x4 zero = {0.f, 0.f, 0.f, 0.f};
  f32x4 ack[4], acv[4];
#pragma unroll
  for (int t = 0; t < 4; ++t) {
    ack[t] = __builtin_amdgcn_mfma_f32_16x16x32_bf16(ak, bk[t], zero, 0, 0, 0);
    acv[t] = __builtin_amdgcn_mfma_f32_16x16x32_bf16(av, bv[t], zero, 0, 0, 0);
  }

  // score per C-row (edge erow+i)
  const int erow = 16 * w + 4 * hi;
  float p0, p1, p2, p3;
  {
    const float* y0 = &ys[(erow + 0) * CPAD + lo];
    const float* y1 = &ys[(erow + 1) * CPAD + lo];
    const float* y2 = &ys[(erow + 2) * CPAD + lo];
    const float* y3 = &ys[(erow + 3) * CPAD + lo];
    p0 = y0[0]*ack[0][0] + y0[16]*ack[1][0] + y0[32]*ack[2][0] + y0[48]*ack[3][0];
    p1 = y1[0]*ack[0][1] + y1[16]*ack[1][1] + y1[32]*ack[2][1] + y1[48]*ack[3][1];
    p2 = y2[0]*ack[0][2] + y2[16]*ack[1][2] + y2[32]*ack[2][2] + y2[48]*ack[3][2];
    p3 = y3[0]*ack[0][3] + y3[16]*ack[1][3] + y3[32]*ack[2][3] + y3[48]*ack[3][3];
  }
#pragma unroll
  for (int off = 1; off < 16; off <<= 1) {
    p0 += __shfl_xor(p0, off);
    p1 += __shfl_xor(p1, off);
    p2 += __shfl_xor(p2, off);
    p3 += __shfl_xor(p3, off);
  }
  float ev0 = cl[erow + 0] * __expf(0.5f * p0);
  float ev1 = cl[erow + 1] * __expf(0.5f * p1);
  float ev2 = cl[erow + 2] * __expf(0.5f * p2);
  float ev3 = cl[erow + 3] * __expf(0.5f * p3);
  float se0 = sqrtf(ev0), se1 = sqrtf(ev1), se2 = sqrtf(ev2), se3 = sqrtf(ev3);
  if (lo < 4) {
    float ev = (lo == 0) ? ev0 : (lo == 1) ? ev1 : (lo == 2) ? ev2 : ev3;
    evs[erow + lo] = ev;
  }
  // msg[e][c] = se * x_src[c] * sv[c]
#pragma unroll
  for (int i = 0; i < 4; ++i) {
    const float se = (i == 0) ? se0 : (i == 1) ? se1 : (i == 2) ? se2 : se3;
    float* mr = &ys[(erow + i) * CPAD + lo];
    const float* xr = &xs[(erow + i) * CPAD + lo];
#pragma unroll
    for (int t = 0; t < 4; ++t) {
      mr[16 * t] = se * xr[16 * t] * acv[t][i];
    }
  }
  // segmented reduce: wave w walks strip [16w,16w+16), lane = channel
  {
    const int c = lane;
    float acc = 0.f, evacc = 0.f;
    int prev = ed[16 * w];
    for (int r = 16 * w; r < 16 * w + 16; ++r) {
      int d = ed[r];
      if (d != prev) {
        unsafeAtomicAdd(&U[prev * 64 + c], acc);
        if (c == 0) unsafeAtomicAdd(&z[prev], evacc);
        acc = 0.f; evacc = 0.f; prev = d;
      }
      acc += ys[r * CPAD + c];
      if (c == 0) evacc += evs[r];
    }
    unsafeAtomicAdd(&U[prev * 64 + c], acc);
    if (c == 0) unsafeAtomicAdd(&z[prev], evacc);
  }
}

// ---------- final (MFMA): out = s*(U@Wlv) + einsum(nf,na,Wsc) ----------
__global__ __launch_bounds__(256) void final_kernel(
    const float* __restrict__ nf, const float* __restrict__ na,
    const float* __restrict__ U, const float* __restrict__ z,
    const unsigned short* __restrict__ wscb, const unsigned short* __restrict__ wlvb,
    float* __restrict__ out)
{
  __shared__ float nfl[64 * 68];
  __shared__ float Ul[64 * 68];
  __shared__ float nal[64 * 17];
  __shared__ float sl[64];
  const int tid = threadIdx.x;
  const int lane = tid & 63;
  const int lo = lane & 15, hi = lane >> 4;
  const int w = tid >> 6;
  const int nb = blockIdx.x * 64;

#pragma unroll
  for (int r = 0; r < 4; ++r) {
    int idx = tid + r * 256;
    int row = idx >> 4, c4 = idx & 15;
    int n = nb + row; if (n >= NN) n = NN - 1;
    float4 v = reinterpret_cast<const float4*>(nf)[n * 16 + c4];
    *reinterpret_cast<float4*>(&nfl[row * 68 + c4 * 4]) = v;
    float4 u = reinterpret_cast<const float4*>(U)[n * 16 + c4];
    *reinterpret_cast<float4*>(&Ul[row * 68 + c4 * 4]) = u;
  }
#pragma unroll
  for (int r = 0; r < 4; ++r) {
    int idx = tid + r * 256;
    int row = idx >> 4, p = idx & 15;
    int n = nb + row; if (n >= NN) n = NN - 1;
    nal[row * 17 + p] = na[n * 16 + p];
  }
  if (tid < 64) {
    int n = nb + tid; if (n >= NN) n = NN - 1;
    float zz = z[n];
    sl[tid] = (zz > 0.f) ? 0.5f * rsqrtf(zz) : 0.f;
  }
  __syncthreads();

  const int row = 16 * w + lo;
  short8v anf[2], au[2];
#pragma unroll
  for (int kk = 0; kk < 2; ++kk) {
#pragma unroll
    for (int j = 0; j < 8; ++j) {
      anf[kk][j] = bf16r(nfl[row * 68 + 32 * kk + 8 * hi + j]);
      au[kk][j]  = bf16r(Ul[row * 68 + 32 * kk + 8 * hi + j]);
    }
  }

  f32x4 zeroA = {0.f, 0.f, 0.f, 0.f};
  f32x4 accS[4] = {zeroA, zeroA, zeroA, zeroA};
  f32x4 accU[4] = {zeroA, zeroA, zeroA, zeroA};

  // U @ Wlv
#pragma unroll
  for (int t = 0; t < 4; ++t) {
    short8v b0 = *reinterpret_cast<const short8v*>(&wlvb[(16 * t + lo) * 64 + 8 * hi]);
    short8v b1 = *reinterpret_cast<const short8v*>(&wlvb[(16 * t + lo) * 64 + 32 + 8 * hi]);
    accU[t] = __builtin_amdgcn_mfma_f32_16x16x32_bf16(au[0], b0, accU[t], 0, 0, 0);
    accU[t] = __builtin_amdgcn_mfma_f32_16x16x32_bf16(au[1], b1, accU[t], 0, 0, 0);
  }
  // sc einsum: 16 p-chunks
  for (int p = 0; p < 16; ++p) {
    f32x4 cp[4] = {zeroA, zeroA, zeroA, zeroA};
#pragma unroll
    for (int t = 0; t < 4; ++t) {
      const int bbase = (p * 64 + 16 * t + lo) * 64 + 8 * hi;
      short8v b0 = *reinterpret_cast<const short8v*>(&wscb[bbase]);
      short8v b1 = *reinterpret_cast<const short8v*>(&wscb[bbase + 32]);
      cp[t] = __builtin_amdgcn_mfma_f32_16x16x32_bf16(anf[0], b0, cp[t], 0, 0, 0);
      cp[t] = __builtin_amdgcn_mfma_f32_16x16x32_bf16(anf[1], b1, cp[t], 0, 0, 0);
    }
#pragma unroll
    for (int i = 0; i < 4; ++i) {
      float nav = nal[(16 * w + 4 * hi + i) * 17 + p];
#pragma unroll
      for (int t = 0; t < 4; ++t) accS[t][i] = fmaf(nav, cp[t][i], accS[t][i]);
    }
  }
  // write out
#pragma unroll
  for (int i = 0; i < 4; ++i) {
    int n = nb + 16 * w + 4 * hi + i;
    if (n < NN) {
      float s = sl[16 * w + 4 * hi + i];
#pragma unroll
      for (int t = 0; t < 4; ++t) {
        out[n * 64 + 16 * t + lo] = fmaf(s, accU[t][i], accS[t][i]);
      }
    }
  }
}

extern "C" void kernel_launch(void* const* d_in, const int* in_sizes, int n_in,
                              void* d_out, int out_size, void* d_ws, size_t ws_size,
                              hipStream_t stream) {
  const float* nf   = (const float*)d_in[0];
  const float* na   = (const float*)d_in[1];
  const float* eb   = (const float*)d_in[2];
  const float* ea   = (const float*)d_in[3];
  const float* pos  = (const float*)d_in[4];
  const int*   esrc = (const int*)d_in[5];
  const int*   edst = (const int*)d_in[6];
  const float* Wq   = (const float*)d_in[7];
  const float* W1k  = (const float*)d_in[8];
  const float* W2k  = (const float*)d_in[9];
  const float* W1v  = (const float*)d_in[10];
  const float* W2v  = (const float*)d_in[11];
  const float* Wlk  = (const float*)d_in[12];
  const float* Wlv  = (const float*)d_in[13];
  const float* Wdot = (const float*)d_in[14];
  const float* Wsc  = (const float*)d_in[15];
  float* out = (float*)d_out;

  float* wsf = (float*)d_ws;
  float* z    = wsf;                       // 50,176
  float* U    = wsf + 50176;               // 3,200,000
  int*   cur  = (int*)(wsf + 50176);       // overlay in U
  int*   bsum = (int*)(wsf + 100352);      // overlay in U
  float* M    = wsf + 100608;              // overlay in U (4,096)
  float* tq   = wsf + 3250176;             // 3,200,000
  unsigned short* wscb = (unsigned short*)(wsf + 3250176);  // overlay on tq (post-edge)
  unsigned short* w2kT = (unsigned short*)(wsf + 6450176);
  unsigned short* w2vT = (unsigned short*)(wsf + 6451200);
  unsigned short* wlvb = (unsigned short*)(wsf + 6452224);
  float* rec  = wsf + 6454272;             // 12,800,000 (64 B/edge)

  fold_kernel<<<1, 256, 0, stream>>>(Wq, Wdot, Wlk, W2k, W2v, Wlv, M, w2kT, w2vT, wlvb);
  tq_kernel<<<(NN + 63) / 64, 256, 0, stream>>>(nf, M, tq);
  hipMemsetAsync(cur, 0, (size_t)(NPAD + 256) * sizeof(int), stream);
  hist_kernel<<<EE / 256, 256, 0, stream>>>(edst, cur);
  scanA_kernel<<<NPAD / 256, 256, 0, stream>>>(cur, bsum);
  scanB_kernel<<<1, 256, 0, stream>>>(bsum);
  scanC_kernel<<<NPAD / 256, 256, 0, stream>>>(cur, bsum);
  scatter_fused<<<EE / 256, 256, 0, stream>>>(esrc, edst, ea, eb, pos, W1k, W1v, cur, rec);
  hipMemsetAsync(z, 0, (size_t)3250176 * sizeof(float), stream);  // z + U (kills cur/bsum/M)
  edge_kernel<<<EE / 64, 256, 0, stream>>>(nf, tq, rec, w2kT, w2vT, z, U);
  prep_wsc<<<256, 256, 0, stream>>>(Wsc, wscb);
  final_kernel<<<(NN + 63) / 64, 256, 0, stream>>>(nf, na, U, z, wscb, wlvb, out);
}

// Round 7
// 316.440 us; speedup vs baseline: 1.4873x; 1.0428x over previous
//
#include <hip/hip_runtime.h>
#include <math.h>

#define NN 50000
#define EE 800000
#define NPAD 50176   // 196*256
#define CPAD 68

typedef __attribute__((ext_vector_type(8))) short short8v;
typedef __attribute__((ext_vector_type(4))) float f32x4;

static __device__ __forceinline__ short bf16r(float x) {
  union { float f; unsigned u; } v; v.f = x;
  unsigned r = v.u + 0x7FFFu + ((v.u >> 16) & 1u);
  return (short)(r >> 16);
}
static __device__ __forceinline__ float bf2f(unsigned u) {
  union { unsigned u; float f; } v; v.u = u << 16;
  return v.f;
}
static __device__ __forceinline__ unsigned pk2(float a, float b) {
  return (unsigned)(unsigned short)bf16r(a) | ((unsigned)(unsigned short)bf16r(b) << 16);
}

// ws layout (float offsets), total 19,254,272 floats = 77.017 MB:
//   z     @ 0           50,176
//   U     @ 50,176      3,200,000   [overlays: cur @50,176 (50,176 int) | bsum @100,352 (256) | M @100,608 (4,096)]
//   tq    @ 3,250,176   3,200,000   [overlay after edge: wscb (65,536 bf16)]
//   w2kT  @ 6,450,176   1,024
//   w2vT  @ 6,451,200   1,024
//   wlvb  @ 6,452,224   2,048
//   rec   @ 6,454,272   12,800,000  (64 B per edge)
// rec: [0]=src [1]=dst [2]=cl [3]=pad [4..7]=ea f32x4 [8..11]=hk bf16x8 [12..15]=hv bf16x8
// order: fold -> tq -> memset(cur+bsum) -> hist -> scanA/B/C -> scatter
//        -> memset(z+U) -> edge -> prep_wsc -> final   (all plain launches; no coop)

// ---------- fold: M = (W_q@W_dot)@W_lin_k^T ; W2{k,v}->bf16 frag layout; Wlv->bf16 [o][c] ----------
__global__ __launch_bounds__(256) void fold_kernel(
    const float* __restrict__ Wq, const float* __restrict__ Wdot,
    const float* __restrict__ Wlk, const float* __restrict__ W2k,
    const float* __restrict__ W2v, const float* __restrict__ Wlv,
    float* __restrict__ M, unsigned short* __restrict__ w2kT,
    unsigned short* __restrict__ w2vT, unsigned short* __restrict__ wlvb)
{
  __shared__ float tmp[2048];
  const int tid = threadIdx.x;
#pragma unroll
  for (int r = 0; r < 8; ++r) {
    int idx = tid + r * 256;
    int cin = idx >> 5, d = idx & 31;
    float a = 0.f;
    for (int j = 0; j < 32; ++j) a = fmaf(Wq[cin * 32 + j], Wdot[j * 32 + d], a);
    tmp[idx] = a;
  }
  __syncthreads();
#pragma unroll
  for (int r = 0; r < 16; ++r) {
    int idx = tid + r * 256;
    int cin = idx >> 6, c = idx & 63;
    float a = 0.f;
    for (int d = 0; d < 32; ++d) a = fmaf(tmp[cin * 32 + d], Wlk[c * 32 + d], a);
    M[idx] = a;
  }
#pragma unroll
  for (int r = 0; r < 8; ++r) {
    int idx = tid + r * 256;
    int c = idx >> 5, k = idx & 31, h = k >> 2, a = k & 3;
    w2kT[idx] = (unsigned short)bf16r(W2k[h * 256 + c * 4 + a]);
    w2vT[idx] = (unsigned short)bf16r(W2v[h * 256 + c * 4 + a]);
  }
#pragma unroll
  for (int r = 0; r < 16; ++r) {
    int idx = tid + r * 256;
    int o = idx >> 6, c = idx & 63;
    wlvb[idx] = (unsigned short)bf16r(Wlv[c * 64 + o]);
  }
}

// ---------- Wscb[(p*64+o)*64+c] = bf16(Wsc[c*1024 + p*64 + o]) ----------
__global__ __launch_bounds__(256) void prep_wsc(
    const float* __restrict__ Wsc, unsigned short* __restrict__ wscb)
{
  int w = blockIdx.x * 256 + threadIdx.x;
  int c = w & 63, o = (w >> 6) & 63, p = w >> 12;
  wscb[w] = (unsigned short)bf16r(Wsc[c * 1024 + p * 64 + o]);
}

// ---------- counting sort (in-place in cur) ----------
__global__ __launch_bounds__(256) void hist_kernel(
    const int* __restrict__ edst, int* __restrict__ cur)
{
  int e = blockIdx.x * 256 + threadIdx.x;
  atomicAdd(&cur[edst[e]], 1);
}

__global__ __launch_bounds__(256) void scanA_kernel(
    int* __restrict__ cur, int* __restrict__ bsum)
{
  __shared__ int s[256];
  const int tid = threadIdx.x;
  const int i = blockIdx.x * 256 + tid;
  int v = cur[i];
  s[tid] = v;
  __syncthreads();
  for (int off = 1; off < 256; off <<= 1) {
    int t = (tid >= off) ? s[tid - off] : 0;
    __syncthreads();
    s[tid] += t;
    __syncthreads();
  }
  cur[i] = s[tid] - v;
  if (tid == 255) bsum[blockIdx.x] = s[255];
}

__global__ __launch_bounds__(256) void scanB_kernel(int* __restrict__ bsum)
{
  __shared__ int s[256];
  const int tid = threadIdx.x;
  int v = (tid < 196) ? bsum[tid] : 0;
  s[tid] = v;
  __syncthreads();
  for (int off = 1; off < 256; off <<= 1) {
    int t = (tid >= off) ? s[tid - off] : 0;
    __syncthreads();
    s[tid] += t;
    __syncthreads();
  }
  if (tid < 196) bsum[tid] = s[tid] - v;
}

__global__ __launch_bounds__(256) void scanC_kernel(
    int* __restrict__ cur, const int* __restrict__ bsum)
{
  const int i = blockIdx.x * 256 + threadIdx.x;
  cur[i] += bsum[blockIdx.x];
}

// ---------- fused scatter: one 64B record per edge at rank r ----------
__global__ __launch_bounds__(256) void scatter_fused(
    const int* __restrict__ esrc, const int* __restrict__ edst,
    const float* __restrict__ ea, const float* __restrict__ eb,
    const float* __restrict__ pos, const float* __restrict__ W1k,
    const float* __restrict__ W1v, int* __restrict__ cur,
    float* __restrict__ rec)
{
  int e = blockIdx.x * 256 + threadIdx.x;
  int s = esrc[e], d = edst[e];
  int r = atomicAdd(&cur[d], 1);
  float dx = pos[d * 3 + 0] - pos[s * 3 + 0];
  float dy = pos[d * 3 + 1] - pos[s * 3 + 1];
  float dz = pos[d * 3 + 2] - pos[s * 3 + 2];
  float len = sqrtf(fmaf(dx, dx, fmaf(dy, dy, dz * dz)));
  float arg = 10.f - 2.f * len;
  float cl = (arg > 0.f) ? __expf(-1.f / arg) : 0.f;
  // radial MLP (f32)
  const float4* eb4 = reinterpret_cast<const float4*>(eb);
  float4 q0 = eb4[e * 4 + 0], q1 = eb4[e * 4 + 1],
         q2 = eb4[e * 4 + 2], q3 = eb4[e * 4 + 3];
  float ebv[16] = {q0.x, q0.y, q0.z, q0.w, q1.x, q1.y, q1.z, q1.w,
                   q2.x, q2.y, q2.z, q2.w, q3.x, q3.y, q3.z, q3.w};
  float h[16];
#pragma unroll
  for (int j = 0; j < 16; ++j) h[j] = 0.f;
#pragma unroll
  for (int b = 0; b < 16; ++b) {
    float x = ebv[b];
#pragma unroll
    for (int j = 0; j < 8; ++j) {
      h[j]     = fmaf(x, W1k[b * 8 + j], h[j]);
      h[8 + j] = fmaf(x, W1v[b * 8 + j], h[8 + j]);
    }
  }
#pragma unroll
  for (int j = 0; j < 16; ++j) h[j] = h[j] / (1.f + __expf(-h[j]));  // silu

  float* rp = rec + (size_t)r * 16;
  float4 w0;
  w0.x = __int_as_float(s); w0.y = __int_as_float(d); w0.z = cl; w0.w = 0.f;
  reinterpret_cast<float4*>(rp)[0] = w0;
  reinterpret_cast<float4*>(rp)[1] = reinterpret_cast<const float4*>(ea)[e];
  float4 w2, w3;
  w2.x = __uint_as_float(pk2(h[0], h[1]));
  w2.y = __uint_as_float(pk2(h[2], h[3]));
  w2.z = __uint_as_float(pk2(h[4], h[5]));
  w2.w = __uint_as_float(pk2(h[6], h[7]));
  w3.x = __uint_as_float(pk2(h[8], h[9]));
  w3.y = __uint_as_float(pk2(h[10], h[11]));
  w3.z = __uint_as_float(pk2(h[12], h[13]));
  w3.w = __uint_as_float(pk2(h[14], h[15]));
  reinterpret_cast<float4*>(rp)[2] = w2;
  reinterpret_cast<float4*>(rp)[3] = w3;
}

// ---------- tq = nf @ M ----------
__global__ __launch_bounds__(256) void tq_kernel(
    const float* __restrict__ nf, const float* __restrict__ M, float* __restrict__ tq)
{
  __shared__ float Ml[4096];
  __shared__ float nfl[64 * 68];
  const int tid = threadIdx.x;
  const int base = blockIdx.x * 64;
#pragma unroll
  for (int r = 0; r < 4; ++r) {
    int idx = tid + r * 256;
    reinterpret_cast<float4*>(Ml)[idx] = reinterpret_cast<const float4*>(M)[idx];
  }
#pragma unroll
  for (int r = 0; r < 4; ++r) {
    int idx = tid + r * 256;
    int row = idx >> 4, c4 = idx & 15;
    float4 v = make_float4(0.f, 0.f, 0.f, 0.f);
    if (base + row < NN) v = reinterpret_cast<const float4*>(nf)[(base + row) * 16 + c4];
    *reinterpret_cast<float4*>(&nfl[row * 68 + c4 * 4]) = v;
  }
  __syncthreads();
  const int to = tid & 15, tn = tid >> 4;
  float4 acc[4] = {make_float4(0,0,0,0), make_float4(0,0,0,0),
                   make_float4(0,0,0,0), make_float4(0,0,0,0)};
  for (int c = 0; c < 64; ++c) {
    float4 m = reinterpret_cast<const float4*>(Ml)[c * 16 + to];
#pragma unroll
    for (int i = 0; i < 4; ++i) {
      float x = nfl[(tn * 4 + i) * 68 + c];
      acc[i].x = fmaf(x, m.x, acc[i].x);
      acc[i].y = fmaf(x, m.y, acc[i].y);
      acc[i].z = fmaf(x, m.z, acc[i].z);
      acc[i].w = fmaf(x, m.w, acc[i].w);
    }
  }
#pragma unroll
  for (int i = 0; i < 4; ++i) {
    int n = base + tn * 4 + i;
    if (n < NN) reinterpret_cast<float4*>(tq)[n * 16 + to] = acc[i];
  }
}

// ---------- edge pass: 64 sorted edges/block, xs-only staging, tq read direct ----------
__global__ __launch_bounds__(256) void edge_kernel(
    const float* __restrict__ nf, const float* __restrict__ tq,
    const float* __restrict__ rec,
    const unsigned short* __restrict__ w2kT, const unsigned short* __restrict__ w2vT,
    float* __restrict__ z, float* __restrict__ U)
{
  __shared__ float xs[64 * CPAD];   // x_src; overwritten with msg
  __shared__ int   es[64];
  __shared__ int   ed[64];
  __shared__ float cl[64];
  __shared__ float evs[64];
  const int tid  = threadIdx.x;
  const int lane = tid & 63;
  const int lo = lane & 15, hi = lane >> 4;
  const int w = tid >> 6;
  const int sb = blockIdx.x * 64;
  const int row = 16 * w + lo;

  // B fragments (loop-invariant)
  short8v bk[4], bv[4];
#pragma unroll
  for (int t = 0; t < 4; ++t) {
    bk[t] = *reinterpret_cast<const short8v*>(&w2kT[(16 * t + lo) * 32 + hi * 8]);
    bv[t] = *reinterpret_cast<const short8v*>(&w2vT[(16 * t + lo) * 32 + hi * 8]);
  }
  // header: one thread per edge
  if (tid < 64) {
    float4 h0 = *reinterpret_cast<const float4*>(rec + (size_t)(sb + tid) * 16);
    es[tid] = __float_as_int(h0.x);
    ed[tid] = __float_as_int(h0.y);
    cl[tid] = h0.z;
  }
  // per-lane A-fragment inputs (linear region, L1/L2)
  const unsigned* ru = reinterpret_cast<const unsigned*>(rec);
  const size_t rb = (size_t)(sb + row) * 16;
  unsigned k01 = ru[rb + 8 + hi];
  unsigned v01 = ru[rb + 12 + hi];
  float4 a4 = *reinterpret_cast<const float4*>(rec + rb + 4);

  __syncthreads();  // es ready

  // stage x_src only (float4 aligned: CPAD=68 divisible by 4)
#pragma unroll
  for (int r = 0; r < 4; ++r) {
    int idx = tid + r * 256;
    int e = idx >> 4, c4 = idx & 15;
    float4 xv = reinterpret_cast<const float4*>(nf)[es[e] * 16 + c4];
    *reinterpret_cast<float4*>(&xs[e * CPAD + c4 * 4]) = xv;
  }

  // build A fragments while staging is in flight
  float hk0 = bf2f(k01 & 0xffffu), hk1 = bf2f(k01 >> 16);
  float hv0 = bf2f(v01 & 0xffffu), hv1 = bf2f(v01 >> 16);
  short8v ak, av;
  ak[0] = bf16r(hk0 * a4.x); ak[1] = bf16r(hk0 * a4.y);
  ak[2] = bf16r(hk0 * a4.z); ak[3] = bf16r(hk0 * a4.w);
  ak[4] = bf16r(hk1 * a4.x); ak[5] = bf16r(hk1 * a4.y);
  ak[6] = bf16r(hk1 * a4.z); ak[7] = bf16r(hk1 * a4.w);
  av[0] = bf16r(hv0 * a4.x); av[1] = bf16r(hv0 * a4.y);
  av[2] = bf16r(hv0 * a4.z); av[3] = bf16r(hv0 * a4.w);
  av[4] = bf16r(hv1 * a4.x); av[5] = bf16r(hv1 * a4.y);
  av[6] = bf16r(hv1 * a4.z); av[7] = bf16r(hv1 * a4.w);

  __syncthreads();  // xs ready

  f32x4 zero = {0.f, 0.f, 0.f, 0.f};
  f32x4 ack[4], acv[4];
#pragma unroll
  for (int t = 0; t < 4; ++t) {
    ack[t] = __builtin_amdgcn_mfma_f32_16x16x32_bf16(ak, bk[t], zero, 0, 0, 0);
    acv[t] = __builtin_amdgcn_mfma_f32_16x16x32_bf16(av, bv[t], zero, 0, 0, 0);
  }

  // score per C-row (edge erow+i): xs from LDS, tq direct from global (L1-hot, dst-sorted)
  const int erow = 16 * w + 4 * hi;
  float p0, p1, p2, p3;
  {
    const float* x0 = &xs[(erow + 0) * CPAD + lo];
    const float* x1 = &xs[(erow + 1) * CPAD + lo];
    const float* x2 = &xs[(erow + 2) * CPAD + lo];
    const float* x3 = &xs[(erow + 3) * CPAD + lo];
    const float* t0 = tq + (size_t)ed[erow + 0] * 64 + lo;
    const float* t1 = tq + (size_t)ed[erow + 1] * 64 + lo;
    const float* t2 = tq + (size_t)ed[erow + 2] * 64 + lo;
    const float* t3 = tq + (size_t)ed[erow + 3] * 64 + lo;
    p0 = (x0[0]*t0[0])*ack[0][0] + (x0[16]*t0[16])*ack[1][0] + (x0[32]*t0[32])*ack[2][0] + (x0[48]*t0[48])*ack[3][0];
    p1 = (x1[0]*t1[0])*ack[0][1] + (x1[16]*t1[16])*ack[1][1] + (x1[32]*t1[32])*ack[2][1] + (x1[48]*t1[48])*ack[3][1];
    p2 = (x2[0]*t2[0])*ack[0][2] + (x2[16]*t2[16])*ack[1][2] + (x2[32]*t2[32])*ack[2][2] + (x2[48]*t2[48])*ack[3][2];
    p3 = (x3[0]*t3[0])*ack[0][3] + (x3[16]*t3[16])*ack[1][3] + (x3[32]*t3[32])*ack[2][3] + (x3[48]*t3[48])*ack[3][3];
  }
#pragma unroll
  for (int off = 1; off < 16; off <<= 1) {
    p0 += __shfl_xor(p0, off);
    p1 += __shfl_xor(p1, off);
    p2 += __shfl_xor(p2, off);
    p3 += __shfl_xor(p3, off);
  }
  float ev0 = cl[erow + 0] * __expf(0.5f * p0);
  float ev1 = cl[erow + 1] * __expf(0.5f * p1);
  float ev2 = cl[erow + 2] * __expf(0.5f * p2);
  float ev3 = cl[erow + 3] * __expf(0.5f * p3);
  float se0 = sqrtf(ev0), se1 = sqrtf(ev1), se2 = sqrtf(ev2), se3 = sqrtf(ev3);
  if (lo < 4) {
    float ev = (lo == 0) ? ev0 : (lo == 1) ? ev1 : (lo == 2) ? ev2 : ev3;
    evs[erow + lo] = ev;
  }
  // msg[e][c] = se * x_src[c] * sv[c]  (overwrite own wave's xs rows; wave-internal order)
#pragma unroll
  for (int i = 0; i < 4; ++i) {
    const float se = (i == 0) ? se0 : (i == 1) ? se1 : (i == 2) ? se2 : se3;
    float* xr = &xs[(erow + i) * CPAD + lo];
#pragma unroll
    for (int t = 0; t < 4; ++t) {
      xr[16 * t] = se * xr[16 * t] * acv[t][i];
    }
  }
  // segmented reduce: wave w walks its own strip [16w,16w+16), lane = channel
  {
    const int c = lane;
    float acc = 0.f, evacc = 0.f;
    int prev = ed[16 * w];
    for (int r = 16 * w; r < 16 * w + 16; ++r) {
      int d = ed[r];
      if (d != prev) {
        unsafeAtomicAdd(&U[prev * 64 + c], acc);
        if (c == 0) unsafeAtomicAdd(&z[prev], evacc);
        acc = 0.f; evacc = 0.f; prev = d;
      }
      acc += xs[r * CPAD + c];
      if (c == 0) evacc += evs[r];
    }
    unsafeAtomicAdd(&U[prev * 64 + c], acc);
    if (c == 0) unsafeAtomicAdd(&z[prev], evacc);
  }
}

// ---------- final (MFMA): out = s*(U@Wlv) + einsum(nf,na,Wsc) ----------
__global__ __launch_bounds__(256) void final_kernel(
    const float* __restrict__ nf, const float* __restrict__ na,
    const float* __restrict__ U, const float* __restrict__ z,
    const unsigned short* __restrict__ wscb, const unsigned short* __restrict__ wlvb,
    float* __restrict__ out)
{
  __shared__ float nfl[64 * 68];
  __shared__ float Ul[64 * 68];
  __shared__ float nal[64 * 17];
  __shared__ float sl[64];
  const int tid = threadIdx.x;
  const int lane = tid & 63;
  const int lo = lane & 15, hi = lane >> 4;
  const int w = tid >> 6;
  const int nb = blockIdx.x * 64;

#pragma unroll
  for (int r = 0; r < 4; ++r) {
    int idx = tid + r * 256;
    int row = idx >> 4, c4 = idx & 15;
    int n = nb + row; if (n >= NN) n = NN - 1;
    float4 v = reinterpret_cast<const float4*>(nf)[n * 16 + c4];
    *reinterpret_cast<float4*>(&nfl[row * 68 + c4 * 4]) = v;
    float4 u = reinterpret_cast<const float4*>(U)[n * 16 + c4];
    *reinterpret_cast<float4*>(&Ul[row * 68 + c4 * 4]) = u;
  }
#pragma unroll
  for (int r = 0; r < 4; ++r) {
    int idx = tid + r * 256;
    int row = idx >> 4, p = idx & 15;
    int n = nb + row; if (n >= NN) n = NN - 1;
    nal[row * 17 + p] = na[n * 16 + p];
  }
  if (tid < 64) {
    int n = nb + tid; if (n >= NN) n = NN - 1;
    float zz = z[n];
    sl[tid] = (zz > 0.f) ? 0.5f * rsqrtf(zz) : 0.f;
  }
  __syncthreads();

  const int row = 16 * w + lo;
  short8v anf[2], au[2];
#pragma unroll
  for (int kk = 0; kk < 2; ++kk) {
#pragma unroll
    for (int j = 0; j < 8; ++j) {
      anf[kk][j] = bf16r(nfl[row * 68 + 32 * kk + 8 * hi + j]);
      au[kk][j]  = bf16r(Ul[row * 68 + 32 * kk + 8 * hi + j]);
    }
  }

  f32x4 zeroA = {0.f, 0.f, 0.f, 0.f};
  f32x4 accS[4] = {zeroA, zeroA, zeroA, zeroA};
  f32x4 accU[4] = {zeroA, zeroA, zeroA, zeroA};

  // U @ Wlv
#pragma unroll
  for (int t = 0; t < 4; ++t) {
    short8v b0 = *reinterpret_cast<const short8v*>(&wlvb[(16 * t + lo) * 64 + 8 * hi]);
    short8v b1 = *reinterpret_cast<const short8v*>(&wlvb[(16 * t + lo) * 64 + 32 + 8 * hi]);
    accU[t] = __builtin_amdgcn_mfma_f32_16x16x32_bf16(au[0], b0, accU[t], 0, 0, 0);
    accU[t] = __builtin_amdgcn_mfma_f32_16x16x32_bf16(au[1], b1, accU[t], 0, 0, 0);
  }
  // sc einsum: 16 p-chunks
  for (int p = 0; p < 16; ++p) {
    f32x4 cp[4] = {zeroA, zeroA, zeroA, zeroA};
#pragma unroll
    for (int t = 0; t < 4; ++t) {
      const int bbase = (p * 64 + 16 * t + lo) * 64 + 8 * hi;
      short8v b0 = *reinterpret_cast<const short8v*>(&wscb[bbase]);
      short8v b1 = *reinterpret_cast<const short8v*>(&wscb[bbase + 32]);
      cp[t] = __builtin_amdgcn_mfma_f32_16x16x32_bf16(anf[0], b0, cp[t], 0, 0, 0);
      cp[t] = __builtin_amdgcn_mfma_f32_16x16x32_bf16(anf[1], b1, cp[t], 0, 0, 0);
    }
#pragma unroll
    for (int i = 0; i < 4; ++i) {
      float nav = nal[(16 * w + 4 * hi + i) * 17 + p];
#pragma unroll
      for (int t = 0; t < 4; ++t) accS[t][i] = fmaf(nav, cp[t][i], accS[t][i]);
    }
  }
  // write out
#pragma unroll
  for (int i = 0; i < 4; ++i) {
    int n = nb + 16 * w + 4 * hi + i;
    if (n < NN) {
      float s = sl[16 * w + 4 * hi + i];
#pragma unroll
      for (int t = 0; t < 4; ++t) {
        out[n * 64 + 16 * t + lo] = fmaf(s, accU[t][i], accS[t][i]);
      }
    }
  }
}

extern "C" void kernel_launch(void* const* d_in, const int* in_sizes, int n_in,
                              void* d_out, int out_size, void* d_ws, size_t ws_size,
                              hipStream_t stream) {
  const float* nf   = (const float*)d_in[0];
  const float* na   = (const float*)d_in[1];
  const float* eb   = (const float*)d_in[2];
  const float* ea   = (const float*)d_in[3];
  const float* pos  = (const float*)d_in[4];
  const int*   esrc = (const int*)d_in[5];
  const int*   edst = (const int*)d_in[6];
  const float* Wq   = (const float*)d_in[7];
  const float* W1k  = (const float*)d_in[8];
  const float* W2k  = (const float*)d_in[9];
  const float* W1v  = (const float*)d_in[10];
  const float* W2v  = (const float*)d_in[11];
  const float* Wlk  = (const float*)d_in[12];
  const float* Wlv  = (const float*)d_in[13];
  const float* Wdot = (const float*)d_in[14];
  const float* Wsc  = (const float*)d_in[15];
  float* out = (float*)d_out;

  float* wsf = (float*)d_ws;
  float* z    = wsf;                       // 50,176
  float* U    = wsf + 50176;               // 3,200,000
  int*   cur  = (int*)(wsf + 50176);       // overlay in U
  int*   bsum = (int*)(wsf + 100352);      // overlay in U
  float* M    = wsf + 100608;              // overlay in U (4,096)
  float* tq   = wsf + 3250176;             // 3,200,000
  unsigned short* wscb = (unsigned short*)(wsf + 3250176);  // overlay on tq (post-edge)
  unsigned short* w2kT = (unsigned short*)(wsf + 6450176);
  unsigned short* w2vT = (unsigned short*)(wsf + 6451200);
  unsigned short* wlvb = (unsigned short*)(wsf + 6452224);
  float* rec  = wsf + 6454272;             // 12,800,000 (64 B/edge)

  fold_kernel<<<1, 256, 0, stream>>>(Wq, Wdot, Wlk, W2k, W2v, Wlv, M, w2kT, w2vT, wlvb);
  tq_kernel<<<(NN + 63) / 64, 256, 0, stream>>>(nf, M, tq);
  hipMemsetAsync(cur, 0, (size_t)(NPAD + 256) * sizeof(int), stream);
  hist_kernel<<<EE / 256, 256, 0, stream>>>(edst, cur);
  scanA_kernel<<<NPAD / 256, 256, 0, stream>>>(cur, bsum);
  scanB_kernel<<<1, 256, 0, stream>>>(bsum);
  scanC_kernel<<<NPAD / 256, 256, 0, stream>>>(cur, bsum);
  scatter_fused<<<EE / 256, 256, 0, stream>>>(esrc, edst, ea, eb, pos, W1k, W1v, cur, rec);
  hipMemsetAsync(z, 0, (size_t)3250176 * sizeof(float), stream);  // z + U (kills cur/bsum/M)
  edge_kernel<<<EE / 64, 256, 0, stream>>>(nf, tq, rec, w2kT, w2vT, z, U);
  prep_wsc<<<256, 256, 0, stream>>>(Wsc, wscb);
  final_kernel<<<(NN + 63) / 64, 256, 0, stream>>>(nf, na, U, z, wscb, wlvb, out);
}